// Round 8
// baseline (706.192 us; speedup 1.0000x reference)
//
#include <hip/hip_runtime.h>
#include <hip/hip_fp16.h>
#include <stdint.h>

static constexpr int Bn = 16, Tn = 2048, En = 1024, NHn = 16, HDn = 64, NLEVn = 12;

typedef __attribute__((ext_vector_type(8))) short short8;
typedef __attribute__((ext_vector_type(4))) float floatx4;

__device__ __forceinline__ unsigned short f2bf(float f) {
  unsigned int u = __float_as_uint(f);
  u += 0x7fffu + ((u >> 16) & 1u);
  return (unsigned short)(u >> 16);
}
__device__ __forceinline__ float bf2f(unsigned short s) {
  return __uint_as_float(((unsigned int)s) << 16);
}

__device__ __forceinline__ void async16(const unsigned short* g, unsigned short* l) {
  __builtin_amdgcn_global_load_lds(
      (const __attribute__((address_space(1))) unsigned int*)g,
      (__attribute__((address_space(3))) unsigned int*)l, 16, 0, 0);
}

// ---------------- fp32 -> bf16 convert ----------------
__global__ void k_cvt(const float* __restrict__ in, unsigned short* __restrict__ out, int n4) {
  int i = blockIdx.x * 256 + threadIdx.x;
  if (i < n4) {
    float4 v = ((const float4*)in)[i];
    ushort4 o;
    o.x = f2bf(v.x); o.y = f2bf(v.y); o.z = f2bf(v.z); o.w = f2bf(v.w);
    ((ushort4*)out)[i] = o;
  }
}

// ---------------- per-head prefix scan of log(sigmoid(A)) -> csT[h][t] ----------------
__global__ void k_scan(const float* __restrict__ A_log, const float* __restrict__ A_bias,
                       float* __restrict__ csT) {
  int h = blockIdx.x;
  int tid = threadIdx.x;
  __shared__ float part[256];
  float loc[8];
  float run = 0.f;
#pragma unroll
  for (int j = 0; j < 8; j++) {
    int t = tid * 8 + j;
    float x = A_log[t * NHn + h] + A_bias[t * NHn + h];
    float ls = -log1pf(__expf(-x));
    run += ls;
    loc[j] = run;
  }
  part[tid] = run;
  __syncthreads();
  for (int d = 1; d < 256; d <<= 1) {
    float v = (tid >= d) ? part[tid - d] : 0.f;
    __syncthreads();
    part[tid] += v;
    __syncthreads();
  }
  float off = (tid > 0) ? part[tid - 1] : 0.f;
#pragma unroll
  for (int j = 0; j < 8; j++) csT[(size_t)h * Tn + tid * 8 + j] = loc[j] + off;
}

// ---------------- gather G[h][t][s] = fp16(L[t][h][lev(t,s)] + Lb) ----------------
// Pure streaming gather (no exp, no cs, no sums): ~128 MiB write.
__global__ void k_gather(const float* __restrict__ L, const float* __restrict__ Lb,
                         const int* __restrict__ levels, unsigned short* __restrict__ G) {
  int t = blockIdx.x;
  int tid = threadIdx.x;
  __shared__ float Lrow[NHn * NLEVn];
  if (tid < NHn * NLEVn) Lrow[tid] = L[t * NHn * NLEVn + tid] + Lb[t * NHn * NLEVn + tid];
  __syncthreads();
  for (int s = tid; s < Tn; s += 256) {
    int lev = levels[(size_t)t * Tn + s];
#pragma unroll
    for (int h = 0; h < NHn; h++) {
      __half hv = __float2half(Lrow[h * NLEVn + lev]);
      G[((size_t)h * Tn + t) * Tn + s] = __half_as_ushort(hv);
    }
  }
}

// ================= GEMM 1: v = x@Wv^T + bv, 256x128 block, fused transpose =================
// (round-0 proven version: 48 KiB LDS, 2 blocks/CU)
__global__ __launch_bounds__(512)
void k_gemm_v(const unsigned short* __restrict__ A, const unsigned short* __restrict__ Bm,
              const float* __restrict__ bias, unsigned short* __restrict__ vt) {
  __shared__ unsigned short smem[24576];     // 48 KB: As(32K) | Bs(16K); epilogue reuses as Ct
  unsigned short* As = smem;                 // 256 x 64
  unsigned short* Bs = smem + 16384;         // 128 x 64
  const int K = 1024;
  int tid = threadIdx.x;
  int wave = tid >> 6, lane = tid & 63;
  int wm = wave >> 1, wn = wave & 1;         // 4 x 2 waves of 64x64 tiles

  int flat = blockIdx.y * 8 + blockIdx.x;    // gridDim.x == 8
  int xcd = flat & 7, slot = flat >> 3;      // slot 0..127
  int strip = xcd * 16 + (slot >> 3);        // 128 strips, 16 per XCD
  int nt = slot & 7;
  int bm = strip * 256, bn = nt * 128;

  floatx4 zero4 = {0.f, 0.f, 0.f, 0.f};
  floatx4 acc[4][4];
#pragma unroll
  for (int i = 0; i < 4; i++)
#pragma unroll
    for (int j = 0; j < 4; j++) acc[i][j] = zero4;

  for (int k0 = 0; k0 < K; k0 += 64) {
    __syncthreads();
#pragma unroll
    for (int j = 0; j < 4; j++) {            // A: 256 rows x 64 k (32KB)
      int f = j * 512 + tid;
      int r = f >> 3, c = f & 7;
      int cg = c ^ (r & 7);
      async16(&A[(size_t)(bm + r) * K + k0 + cg * 8], &As[f * 8]);
    }
#pragma unroll
    for (int j = 0; j < 2; j++) {            // B: 128 rows x 64 k (16KB)
      int f = j * 512 + tid;
      int r = f >> 3, c = f & 7;
      int cg = c ^ (r & 7);
      async16(&Bm[(size_t)(bn + r) * K + k0 + cg * 8], &Bs[f * 8]);
    }
    __syncthreads();
#pragma unroll
    for (int kk = 0; kk < 2; kk++) {
      short8 af[4], bfr[4];
      int cgk = kk * 4 + (lane >> 4);
#pragma unroll
      for (int i = 0; i < 4; i++) {
        int m = wm * 64 + i * 16 + (lane & 15);
        af[i] = *(const short8*)&As[m * 64 + ((cgk ^ (m & 7)) * 8)];
        int n = wn * 64 + i * 16 + (lane & 15);
        bfr[i] = *(const short8*)&Bs[n * 64 + ((cgk ^ (n & 7)) * 8)];
      }
#pragma unroll
      for (int i = 0; i < 4; i++)
#pragma unroll
        for (int j = 0; j < 4; j++)
          acc[i][j] = __builtin_amdgcn_mfma_f32_16x16x32_bf16(af[i], bfr[j], acc[i][j], 0, 0, 0);
    }
  }

  // ---- fused transpose epilogue: write vt[h][b][d][t] ----
  int b = bm >> 11, t0 = bm & 2047;
  unsigned short* Ct = smem;                 // 64 cols x (256+8) rows
  const int S = 264;
#pragma unroll 1
  for (int pass = 0; pass < 2; pass++) {
    __syncthreads();
    if (wn == pass) {
#pragma unroll
      for (int i = 0; i < 4; i++) {
#pragma unroll
        for (int j = 0; j < 4; j++) {
          int colL = j * 16 + (lane & 15);
          float bia = bias[bn + pass * 64 + colL];
          int rowb = wm * 64 + i * 16 + (lane >> 4) * 4;
          ushort4 p;
          p.x = f2bf(acc[i][j][0] + bia);
          p.y = f2bf(acc[i][j][1] + bia);
          p.z = f2bf(acc[i][j][2] + bia);
          p.w = f2bf(acc[i][j][3] + bia);
          *(ushort4*)&Ct[colL * S + rowb] = p;
        }
      }
    }
    __syncthreads();
#pragma unroll
    for (int cc = 0; cc < 4; cc++) {
      int colL = wave * 8 + cc * 2 + (lane >> 5);
      int gc = bn + pass * 64 + colL;
      int h = gc >> 6, d = gc & 63;
      int tt = (lane & 31) * 8;
      short8 v = *(const short8*)&Ct[colL * S + tt];
      *(short8*)&vt[((size_t)((h * Bn + b) * HDn + d)) * Tn + t0 + tt] = v;
    }
  }
}

// ================= shared 256x256 BK=64 macros (round-2 verified) =================

#define STAGE_A(kt, half, buf)                                                   \
  {                                                                              \
    _Pragma("unroll")                                                            \
    for (int j_ = 0; j_ < 2; j_++) {                                             \
      int f_ = j_ * 512 + tid;                                                   \
      int r_ = f_ >> 3, c_ = f_ & 7;                                             \
      int cg_ = c_ ^ (r_ & 7);                                                   \
      async16(&Ap[(size_t)(bm + (half) * 128 + r_) * K + (kt) * 64 + cg_ * 8],   \
              &smem[(buf) * 32768 + ((half) * 128 + r_) * 64 + c_ * 8]);         \
    }                                                                            \
  }

#define STAGE_B(kt, half, buf)                                                   \
  {                                                                              \
    _Pragma("unroll")                                                            \
    for (int j_ = 0; j_ < 2; j_++) {                                             \
      int f_ = j_ * 512 + tid;                                                   \
      int r_ = f_ >> 3, c_ = f_ & 7;                                             \
      int cg_ = c_ ^ (r_ & 7);                                                   \
      async16(&Bp[(size_t)(bn + (half) * 128 + r_) * K + (kt) * 64 + cg_ * 8],   \
              &smem[(buf) * 32768 + 16384 + ((half) * 128 + r_) * 64 + c_ * 8]); \
    }                                                                            \
  }

#define LOAD_A(buf, Mh)                                                          \
  {                                                                              \
    _Pragma("unroll")                                                            \
    for (int ii_ = 0; ii_ < 4; ii_++) {                                          \
      int m_ = (Mh) * 128 + wm * 64 + ii_ * 16 + (lane & 15);                    \
      _Pragma("unroll")                                                          \
      for (int kk_ = 0; kk_ < 2; kk_++) {                                        \
        int cgk_ = kk_ * 4 + (lane >> 4);                                        \
        aR[ii_][kk_] =                                                           \
            *(const short8*)&smem[(buf) * 32768 + m_ * 64 + ((cgk_ ^ (m_ & 7)) * 8)]; \
      }                                                                          \
    }                                                                            \
  }

#define LOAD_B(buf, Nh)                                                          \
  {                                                                              \
    _Pragma("unroll")                                                            \
    for (int jj_ = 0; jj_ < 2; jj_++) {                                          \
      int n_ = (Nh) * 128 + wn * 32 + jj_ * 16 + (lane & 15);                    \
      _Pragma("unroll")                                                          \
      for (int kk_ = 0; kk_ < 2; kk_++) {                                        \
        int cgk_ = kk_ * 4 + (lane >> 4);                                        \
        bR[jj_][kk_] = *(const short8*)&smem[(buf) * 32768 + 16384 + n_ * 64 +   \
                                             ((cgk_ ^ (n_ & 7)) * 8)];           \
      }                                                                          \
    }                                                                            \
  }

#define MFMA16(Mh, Nh)                                                           \
  {                                                                              \
    __builtin_amdgcn_s_setprio(1);                                               \
    _Pragma("unroll")                                                            \
    for (int kk_ = 0; kk_ < 2; kk_++)                                            \
      _Pragma("unroll")                                                          \
      for (int ii_ = 0; ii_ < 4; ii_++)                                          \
        _Pragma("unroll")                                                        \
        for (int jj_ = 0; jj_ < 2; jj_++)                                        \
          acc[(Mh) * 4 + ii_][(Nh) * 2 + jj_] = __builtin_amdgcn_mfma_f32_16x16x32_bf16( \
              aR[ii_][kk_], bR[jj_][kk_], acc[(Mh) * 4 + ii_][(Nh) * 2 + jj_], 0, 0, 0); \
    __builtin_amdgcn_s_setprio(0);                                               \
  }

#define WAIT6 asm volatile("s_waitcnt vmcnt(6)" ::: "memory")
#define WAIT4 asm volatile("s_waitcnt vmcnt(4)" ::: "memory")
#define LGKM0 asm volatile("s_waitcnt lgkmcnt(0)" ::: "memory")
#define BAR                                                                      \
  {                                                                              \
    asm volatile("" ::: "memory");                                               \
    __builtin_amdgcn_s_barrier();                                                \
    asm volatile("" ::: "memory");                                               \
  }

// in-place LDS transform: G(fp16) half-tile -> P(bf16) = exp(G * exp(cst-csr)),
// 1.0 where s > t; accumulates bf16-rounded row sums into dsumR.
#define TRANSFORM(half, buf, kt, cb)                                             \
  {                                                                              \
    int cg_ = (tid & 7) ^ ((tid >> 3) & 7);                                      \
    float4 csA = *(const float4*)&csr_lds[(cb) * 64 + cg_ * 8];                  \
    float4 csBv = *(const float4*)&csr_lds[(cb) * 64 + cg_ * 8 + 4];             \
    int sb_ = (kt) * 64 + cg_ * 8;                                               \
    _Pragma("unroll")                                                            \
    for (int j_ = 0; j_ < 2; j_++) {                                             \
      int r_ = (half) * 128 + j_ * 64 + (tid >> 3);                              \
      int au_ = (buf) * 32768 + r_ * 64 + (tid & 7) * 8;                         \
      short8 g8 = *(const short8*)&smem[au_];                                    \
      float cstv = cst_lds[r_];                                                  \
      int trow_ = bm + r_;                                                       \
      float sum_ = 0.f;                                                          \
      short8 o8;                                                                 \
      _Pragma("unroll")                                                          \
      for (int e_ = 0; e_ < 8; e_++) {                                           \
        float w_ = 1.0f;                                                         \
        if (sb_ + e_ <= trow_) {                                                 \
          __half hh_ = __ushort_as_half((unsigned short)g8[e_]);                 \
          float g_ = __half2float(hh_);                                          \
          float csr_ = (e_ < 4) ? ((const float*)&csA)[e_ & 3]                   \
                                : ((const float*)&csBv)[e_ & 3];                 \
          w_ = __expf(g_ * __expf(cstv - csr_));                                 \
        }                                                                        \
        unsigned short pb_ = f2bf(w_);                                           \
        o8[e_] = (short)pb_;                                                     \
        sum_ += bf2f(pb_);                                                       \
      }                                                                          \
      *(short8*)&smem[au_] = o8;                                                 \
      dsumR[(half) * 2 + j_] += sum_;                                            \
    }                                                                            \
  }

// ================= GEMM 2: fused weights+attn (per head) =================
// A-operand synthesized: G staged like P was, transformed in-LDS off the
// critical path (h1 at P2 tail, h0 of t+1 at P4 tail). Denominator local.
__global__ __launch_bounds__(512, 2)
void k_gemm_attn(const unsigned short* __restrict__ G, const unsigned short* __restrict__ vt,
                 const float* __restrict__ csT, unsigned short* __restrict__ outp) {
  __shared__ unsigned short smem[65536];     // 128 KiB: 2 x (A 256x64 | B 256x64)
  __shared__ float csr_lds[2 * 64];          // per-K-tile cs[s] slice, dbuf
  __shared__ float cst_lds[256];             // cs[t] for this block's rows
  __shared__ float dsum_lds[256];            // row sums (denominator)
  const int K = Tn;
  int tid = threadIdx.x;
  int wave = tid >> 6, lane = tid & 63;
  int wm = wave >> 2, wn = wave & 3;

  int flat = blockIdx.y * 8 + blockIdx.x;    // gridDim = (8, 64)
  int wg = (flat & 7) * 64 + (flat >> 3);
  int h = wg >> 5;
  int mt = (wg >> 2) & 7, nt = wg & 3;
  int bm = mt * 256, bn = nt * 256;

  const unsigned short* Ap = G + (size_t)h * Tn * Tn;
  const unsigned short* Bp = vt + (size_t)h * (Bn * HDn) * Tn;
  const float* csh = csT + (size_t)h * Tn;

  floatx4 zero4 = {0.f, 0.f, 0.f, 0.f};
  floatx4 acc[8][4];
#pragma unroll
  for (int i = 0; i < 8; i++)
#pragma unroll
    for (int j = 0; j < 4; j++) acc[i][j] = zero4;

  short8 aR[4][2], bR[2][2];
  float dsumR[4] = {0.f, 0.f, 0.f, 0.f};

  // prologue: cst + csr(t0) to LDS, stage K-tile 0, transform half0 of tile 0
  if (tid < 256) cst_lds[tid] = csh[bm + tid];
  if (tid < 64) csr_lds[tid] = csh[tid];          // kt=0 slice -> cb 0
  STAGE_A(0, 0, 0);
  STAGE_B(0, 0, 0);
  STAGE_B(0, 1, 0);
  STAGE_A(0, 1, 0);
  __syncthreads();                                 // full drain: A0+csr+cst ready
  TRANSFORM(0, 0, 0, 0);
  LGKM0;

  const int nk = K / 64;                     // 32
  for (int t = 0; t < nk; t++) {
    int buf = t & 1, nbuf = buf ^ 1;
    int tn = (t < nk - 1) ? t + 1 : nk - 1;

    // P1: quadrant (0,0); stage Ah0[t+1] + csr[t+1]
    if (tid < 64) csr_lds[nbuf * 64 + tid] = csh[tn * 64 + tid];
    STAGE_A(tn, 0, nbuf);
    WAIT6; LGKM0; BAR;
    LOAD_A(buf, 0);
    LOAD_B(buf, 0);
    MFMA16(0, 0);
    BAR;
    // P2: quadrant (0,1); stage Bh0[t+1]; transform h1 of tile t (consumer: P3)
    STAGE_B(tn, 0, nbuf);
    WAIT4; BAR;
    LOAD_B(buf, 1);
    MFMA16(0, 1);
    TRANSFORM(1, buf, t, buf);
    LGKM0; BAR;
    // P3: quadrant (1,1)
    STAGE_B(tn, 1, nbuf);
    WAIT6; BAR;
    LOAD_A(buf, 1);
    MFMA16(1, 1);
    BAR;
    // P4: quadrant (1,0); stage Ah1[t+1]; transform h0 of tile t+1 (consumer: next P1)
    STAGE_A(tn, 1, nbuf);
    WAIT6; BAR;
    LOAD_B(buf, 0);
    MFMA16(1, 0);
    if (t < nk - 1) { TRANSFORM(0, nbuf, t + 1, nbuf); }
    LGKM0; BAR;
  }
  asm volatile("s_waitcnt vmcnt(0)" ::: "memory");

  // denominator: reduce 8 chunk-owners per row, publish to LDS
#pragma unroll
  for (int q = 0; q < 4; q++) {
    float v = dsumR[q];
    v += __shfl_xor(v, 1, 64);
    v += __shfl_xor(v, 2, 64);
    v += __shfl_xor(v, 4, 64);
    if ((tid & 7) == 0) dsum_lds[q * 64 + (tid >> 3)] = v;
  }
  __syncthreads();

  // epilogue: scale by 1/denom, scatter col=(b,d) -> outp[b][row][h*64+d]
#pragma unroll
  for (int i = 0; i < 8; i++) {
    int rl = (i >> 2) * 128 + wm * 64 + (i & 3) * 16 + (lane >> 4) * 4;
#pragma unroll
    for (int r = 0; r < 4; r++) {
      int row = bm + rl + r;
      float sc = 1.f / dsum_lds[rl + r];
#pragma unroll
      for (int j = 0; j < 4; j++) {
        int col = bn + (j >> 1) * 128 + wn * 32 + (j & 1) * 16 + (lane & 15);
        int b = col >> 6, d = col & 63;
        outp[((size_t)(b * Tn + row)) * En + h * HDn + d] = f2bf(acc[i][j][r] * sc);
      }
    }
  }
}

// ================= GEMM 3: out = o@Wo^T + bo, 256x256 block (round-2 skeleton) =================
__global__ __launch_bounds__(512, 2)
void k_gemm_out(const unsigned short* __restrict__ A, const unsigned short* __restrict__ Bm,
                const float* __restrict__ bias, float* __restrict__ out) {
  __shared__ unsigned short smem[65536];     // 128 KiB
  const int K = 1024, N = 1024;
  int tid = threadIdx.x;
  int wave = tid >> 6, lane = tid & 63;
  int wm = wave >> 2, wn = wave & 3;

  int flat = blockIdx.y * 8 + blockIdx.x;    // gridDim = (8, 64)
  int wg = (flat & 7) * 64 + (flat >> 3);
  int mt = wg >> 2, nt = wg & 3;
  int bm = mt * 256, bn = nt * 256;

  const unsigned short* Ap = A;
  const unsigned short* Bp = Bm;

  floatx4 zero4 = {0.f, 0.f, 0.f, 0.f};
  floatx4 acc[8][4];
#pragma unroll
  for (int i = 0; i < 8; i++)
#pragma unroll
    for (int j = 0; j < 4; j++) acc[i][j] = zero4;

  short8 aR[4][2], bR[2][2];

  STAGE_A(0, 0, 0);
  STAGE_B(0, 0, 0);
  STAGE_B(0, 1, 0);
  STAGE_A(0, 1, 0);

  const int nk = K / 64;                     // 16
  for (int t = 0; t < nk; t++) {
    int buf = t & 1, nbuf = buf ^ 1;
    int tn = (t < nk - 1) ? t + 1 : nk - 1;
    // P1
    STAGE_A(tn, 0, nbuf);
    WAIT6; BAR;
    LOAD_A(buf, 0);
    LOAD_B(buf, 0);
    MFMA16(0, 0);
    BAR;
    // P2
    STAGE_B(tn, 0, nbuf);
    WAIT6; BAR;
    LOAD_B(buf, 1);
    MFMA16(0, 1);
    BAR;
    // P3
    STAGE_B(tn, 1, nbuf);
    WAIT6; BAR;
    LOAD_A(buf, 1);
    MFMA16(1, 1);
    BAR;
    // P4
    STAGE_A(tn, 1, nbuf);
    WAIT6; BAR;
    LOAD_B(buf, 0);
    MFMA16(1, 0);
    BAR;
  }
  asm volatile("s_waitcnt vmcnt(0)" ::: "memory");

#pragma unroll
  for (int i = 0; i < 8; i++) {
    int rb = bm + (i >> 2) * 128 + wm * 64 + (i & 3) * 16 + (lane >> 4) * 4;
#pragma unroll
    for (int r = 0; r < 4; r++) {
      int row = rb + r;
#pragma unroll
      for (int j = 0; j < 4; j++) {
        int col = bn + (j >> 1) * 128 + wn * 32 + (j & 1) * 16 + (lane & 15);
        out[(size_t)row * N + col] = acc[i][j][r] + bias[col];
      }
    }
  }
}

extern "C" void kernel_launch(void* const* d_in, const int* in_sizes, int n_in,
                              void* d_out, int out_size, void* d_ws, size_t ws_size,
                              hipStream_t stream) {
  const float* x      = (const float*)d_in[0];
  // d_in[1..4] = Wq, bq, Wk, bk — unused by the reference
  const float* Wv     = (const float*)d_in[5];
  const float* bv     = (const float*)d_in[6];
  const float* A_log  = (const float*)d_in[7];
  const float* A_bias = (const float*)d_in[8];
  const float* L      = (const float*)d_in[9];
  const float* Lb     = (const float*)d_in[10];
  const float* Wo     = (const float*)d_in[11];
  const float* bo     = (const float*)d_in[12];
  const int* levels   = (const int*)d_in[13];
  float* out = (float*)d_out;

  // workspace layout (bytes); Gw aliases xb (dead after k_gemm_v)
  char* ws = (char*)d_ws;
  float* csT           = (float*)(ws + 0);                  // 128 KiB (cs, h-major)
  unsigned short* Wvb  = (unsigned short*)(ws + 262144);    // 2 MiB
  unsigned short* Wob  = (unsigned short*)(ws + 2359296);   // 2 MiB
  unsigned short* xb   = (unsigned short*)(ws + 4456448);   // 64 MiB
  unsigned short* Gw   = (unsigned short*)(ws + 4456448);   // 128 MiB (aliases xb)
  unsigned short* vt   = (unsigned short*)(ws + 138674176); // 64 MiB
  unsigned short* outp = (unsigned short*)(ws + 205783040); // 64 MiB
  if (ws_size < 272891904ULL) return;

  int nx4 = Bn * Tn * En / 4;
  k_cvt<<<(nx4 + 255) / 256, 256, 0, stream>>>(x, xb, nx4);
  int nw4 = En * En / 4;
  k_cvt<<<(nw4 + 255) / 256, 256, 0, stream>>>(Wv, Wvb, nw4);
  k_cvt<<<(nw4 + 255) / 256, 256, 0, stream>>>(Wo, Wob, nw4);
  k_scan<<<NHn, 256, 0, stream>>>(A_log, A_bias, csT);

  k_gemm_v<<<dim3(8, 128), 512, 0, stream>>>(xb, Wvb, bv, vt);

  k_gather<<<Tn, 256, 0, stream>>>(L, Lb, levels, Gw);

  k_gemm_attn<<<dim3(8, 64), 512, 0, stream>>>(Gw, vt, csT, outp);

  k_gemm_out<<<dim3(8, 64), 512, 0, stream>>>(outp, Wob, bo, out);
}

// Round 9
// 606.328 us; speedup vs baseline: 1.1647x; 1.1647x over previous
//
#include <hip/hip_runtime.h>
#include <stdint.h>

static constexpr int Bn = 16, Tn = 2048, En = 1024, NHn = 16, HDn = 64, NLEVn = 12;

typedef __attribute__((ext_vector_type(8))) short short8;
typedef __attribute__((ext_vector_type(4))) float floatx4;

__device__ __forceinline__ unsigned short f2bf(float f) {
  unsigned int u = __float_as_uint(f);
  u += 0x7fffu + ((u >> 16) & 1u);
  return (unsigned short)(u >> 16);
}
__device__ __forceinline__ float bf2f(unsigned short s) {
  return __uint_as_float(((unsigned int)s) << 16);
}

__device__ __forceinline__ void async16(const unsigned short* g, unsigned short* l) {
  __builtin_amdgcn_global_load_lds(
      (const __attribute__((address_space(1))) unsigned int*)g,
      (__attribute__((address_space(3))) unsigned int*)l, 16, 0, 0);
}

// ---------------- fp32 -> bf16 convert ----------------
__global__ void k_cvt(const float* __restrict__ in, unsigned short* __restrict__ out, int n4) {
  int i = blockIdx.x * 256 + threadIdx.x;
  if (i < n4) {
    float4 v = ((const float4*)in)[i];
    ushort4 o;
    o.x = f2bf(v.x); o.y = f2bf(v.y); o.z = f2bf(v.z); o.w = f2bf(v.w);
    ((ushort4*)out)[i] = o;
  }
}

// ---------------- per-head prefix scan of log(sigmoid(A)) -> csT[h][t] ----------------
__global__ void k_scan(const float* __restrict__ A_log, const float* __restrict__ A_bias,
                       float* __restrict__ csT) {
  int h = blockIdx.x;
  int tid = threadIdx.x;
  __shared__ float part[256];
  float loc[8];
  float run = 0.f;
#pragma unroll
  for (int j = 0; j < 8; j++) {
    int t = tid * 8 + j;
    float x = A_log[t * NHn + h] + A_bias[t * NHn + h];
    float ls = -log1pf(__expf(-x));
    run += ls;
    loc[j] = run;
  }
  part[tid] = run;
  __syncthreads();
  for (int d = 1; d < 256; d <<= 1) {
    float v = (tid >= d) ? part[tid - d] : 0.f;
    __syncthreads();
    part[tid] += v;
    __syncthreads();
  }
  float off = (tid > 0) ? part[tid - 1] : 0.f;
#pragma unroll
  for (int j = 0; j < 8; j++) csT[(size_t)h * Tn + tid * 8 + j] = loc[j] + off;
}

// ---------------- unnormalized weights P[h][t][s] (bf16) + row sums ----------------
// Round-0 scalar structure (low VGPR, full occupancy), but cs consumed via the
// TRANSPOSED csT[h][t]: csT[h*Tn+s] is coalesced across lanes (4 B/lane,
// consecutive s), replacing the 64 B-lane-strided float4 reads of cs[s][h].
__global__ void k_weights(const float* __restrict__ L, const float* __restrict__ Lb,
                          const int* __restrict__ levels, const float* __restrict__ csT,
                          unsigned short* __restrict__ P, float* __restrict__ denom) {
  int t = blockIdx.x;
  int tid = threadIdx.x;
  __shared__ float Lrow[NHn * NLEVn];
  __shared__ float cst[NHn];
  __shared__ float dsum[NHn];
  if (tid < NHn * NLEVn) Lrow[tid] = L[t * NHn * NLEVn + tid] + Lb[t * NHn * NLEVn + tid];
  if (tid < NHn) { cst[tid] = csT[(size_t)tid * Tn + t]; dsum[tid] = 0.f; }
  __syncthreads();
  float acc[NHn];
#pragma unroll
  for (int h = 0; h < NHn; h++) acc[h] = 0.f;
  for (int s = tid; s < Tn; s += 256) {
    int lev = levels[(size_t)t * Tn + s];
    bool causal = (s <= t);
#pragma unroll
    for (int h = 0; h < NHn; h++) {
      float w = 1.f;   // exp(0) for s > t (mask writes 0, not -inf)
      if (causal) {
        float csr = csT[(size_t)h * Tn + s];      // coalesced: 4 B/lane
        float dec = __expf(cst[h] - csr);
        w = __expf(Lrow[h * NLEVn + lev] * dec);
      }
      unsigned short pb = f2bf(w);
      acc[h] += bf2f(pb);
      P[((size_t)h * Tn + t) * Tn + s] = pb;
    }
  }
  int lane = tid & 63;
#pragma unroll
  for (int h = 0; h < NHn; h++) {
    float v = acc[h];
    for (int o = 32; o > 0; o >>= 1) v += __shfl_down(v, o, 64);
    if (lane == 0) atomicAdd(&dsum[h], v);
  }
  __syncthreads();
  if (tid < NHn) denom[(size_t)tid * Tn + t] = dsum[tid];
}

// ================= GEMM 1: v = x@Wv^T + bv, 256x128 block, fused transpose =================
// (round-0 proven version: 48 KiB LDS, 2 blocks/CU)
__global__ __launch_bounds__(512)
void k_gemm_v(const unsigned short* __restrict__ A, const unsigned short* __restrict__ Bm,
              const float* __restrict__ bias, unsigned short* __restrict__ vt) {
  __shared__ unsigned short smem[24576];     // 48 KB: As(32K) | Bs(16K); epilogue reuses as Ct
  unsigned short* As = smem;                 // 256 x 64
  unsigned short* Bs = smem + 16384;         // 128 x 64
  const int K = 1024;
  int tid = threadIdx.x;
  int wave = tid >> 6, lane = tid & 63;
  int wm = wave >> 1, wn = wave & 1;         // 4 x 2 waves of 64x64 tiles

  int flat = blockIdx.y * 8 + blockIdx.x;    // gridDim.x == 8
  int xcd = flat & 7, slot = flat >> 3;      // slot 0..127
  int strip = xcd * 16 + (slot >> 3);        // 128 strips, 16 per XCD
  int nt = slot & 7;
  int bm = strip * 256, bn = nt * 128;

  floatx4 zero4 = {0.f, 0.f, 0.f, 0.f};
  floatx4 acc[4][4];
#pragma unroll
  for (int i = 0; i < 4; i++)
#pragma unroll
    for (int j = 0; j < 4; j++) acc[i][j] = zero4;

  for (int k0 = 0; k0 < K; k0 += 64) {
    __syncthreads();
#pragma unroll
    for (int j = 0; j < 4; j++) {            // A: 256 rows x 64 k (32KB)
      int f = j * 512 + tid;
      int r = f >> 3, c = f & 7;
      int cg = c ^ (r & 7);
      async16(&A[(size_t)(bm + r) * K + k0 + cg * 8], &As[f * 8]);
    }
#pragma unroll
    for (int j = 0; j < 2; j++) {            // B: 128 rows x 64 k (16KB)
      int f = j * 512 + tid;
      int r = f >> 3, c = f & 7;
      int cg = c ^ (r & 7);
      async16(&Bm[(size_t)(bn + r) * K + k0 + cg * 8], &Bs[f * 8]);
    }
    __syncthreads();
#pragma unroll
    for (int kk = 0; kk < 2; kk++) {
      short8 af[4], bfr[4];
      int cgk = kk * 4 + (lane >> 4);
#pragma unroll
      for (int i = 0; i < 4; i++) {
        int m = wm * 64 + i * 16 + (lane & 15);
        af[i] = *(const short8*)&As[m * 64 + ((cgk ^ (m & 7)) * 8)];
        int n = wn * 64 + i * 16 + (lane & 15);
        bfr[i] = *(const short8*)&Bs[n * 64 + ((cgk ^ (n & 7)) * 8)];
      }
#pragma unroll
      for (int i = 0; i < 4; i++)
#pragma unroll
        for (int j = 0; j < 4; j++)
          acc[i][j] = __builtin_amdgcn_mfma_f32_16x16x32_bf16(af[i], bfr[j], acc[i][j], 0, 0, 0);
    }
  }

  // ---- fused transpose epilogue: write vt[h][b][d][t] ----
  int b = bm >> 11, t0 = bm & 2047;
  unsigned short* Ct = smem;                 // 64 cols x (256+8) rows
  const int S = 264;
#pragma unroll 1
  for (int pass = 0; pass < 2; pass++) {
    __syncthreads();
    if (wn == pass) {
#pragma unroll
      for (int i = 0; i < 4; i++) {
#pragma unroll
        for (int j = 0; j < 4; j++) {
          int colL = j * 16 + (lane & 15);
          float bia = bias[bn + pass * 64 + colL];
          int rowb = wm * 64 + i * 16 + (lane >> 4) * 4;
          ushort4 p;
          p.x = f2bf(acc[i][j][0] + bia);
          p.y = f2bf(acc[i][j][1] + bia);
          p.z = f2bf(acc[i][j][2] + bia);
          p.w = f2bf(acc[i][j][3] + bia);
          *(ushort4*)&Ct[colL * S + rowb] = p;
        }
      }
    }
    __syncthreads();
#pragma unroll
    for (int cc = 0; cc < 4; cc++) {
      int colL = wave * 8 + cc * 2 + (lane >> 5);
      int gc = bn + pass * 64 + colL;
      int h = gc >> 6, d = gc & 63;
      int tt = (lane & 31) * 8;
      short8 v = *(const short8*)&Ct[colL * S + tt];
      *(short8*)&vt[((size_t)((h * Bn + b) * HDn + d)) * Tn + t0 + tt] = v;
    }
  }
}

// ================= shared 256x256 BK=64 macros (round-2 verified) =================

#define STAGE_A(kt, half, buf)                                                   \
  {                                                                              \
    _Pragma("unroll")                                                            \
    for (int j_ = 0; j_ < 2; j_++) {                                             \
      int f_ = j_ * 512 + tid;                                                   \
      int r_ = f_ >> 3, c_ = f_ & 7;                                             \
      int cg_ = c_ ^ (r_ & 7);                                                   \
      async16(&Ap[(size_t)(bm + (half) * 128 + r_) * K + (kt) * 64 + cg_ * 8],   \
              &smem[(buf) * 32768 + ((half) * 128 + r_) * 64 + c_ * 8]);         \
    }                                                                            \
  }

#define STAGE_B(kt, half, buf)                                                   \
  {                                                                              \
    _Pragma("unroll")                                                            \
    for (int j_ = 0; j_ < 2; j_++) {                                             \
      int f_ = j_ * 512 + tid;                                                   \
      int r_ = f_ >> 3, c_ = f_ & 7;                                             \
      int cg_ = c_ ^ (r_ & 7);                                                   \
      async16(&Bp[(size_t)(bn + (half) * 128 + r_) * K + (kt) * 64 + cg_ * 8],   \
              &smem[(buf) * 32768 + 16384 + ((half) * 128 + r_) * 64 + c_ * 8]); \
    }                                                                            \
  }

#define LOAD_A(buf, Mh)                                                          \
  {                                                                              \
    _Pragma("unroll")                                                            \
    for (int ii_ = 0; ii_ < 4; ii_++) {                                          \
      int m_ = (Mh) * 128 + wm * 64 + ii_ * 16 + (lane & 15);                    \
      _Pragma("unroll")                                                          \
      for (int kk_ = 0; kk_ < 2; kk_++) {                                        \
        int cgk_ = kk_ * 4 + (lane >> 4);                                        \
        aR[ii_][kk_] =                                                           \
            *(const short8*)&smem[(buf) * 32768 + m_ * 64 + ((cgk_ ^ (m_ & 7)) * 8)]; \
      }                                                                          \
    }                                                                            \
  }

#define LOAD_B(buf, Nh)                                                          \
  {                                                                              \
    _Pragma("unroll")                                                            \
    for (int jj_ = 0; jj_ < 2; jj_++) {                                          \
      int n_ = (Nh) * 128 + wn * 32 + jj_ * 16 + (lane & 15);                    \
      _Pragma("unroll")                                                          \
      for (int kk_ = 0; kk_ < 2; kk_++) {                                        \
        int cgk_ = kk_ * 4 + (lane >> 4);                                        \
        bR[jj_][kk_] = *(const short8*)&smem[(buf) * 32768 + 16384 + n_ * 64 +   \
                                             ((cgk_ ^ (n_ & 7)) * 8)];           \
      }                                                                          \
    }                                                                            \
  }

#define MFMA16(Mh, Nh)                                                           \
  {                                                                              \
    __builtin_amdgcn_s_setprio(1);                                               \
    _Pragma("unroll")                                                            \
    for (int kk_ = 0; kk_ < 2; kk_++)                                            \
      _Pragma("unroll")                                                          \
      for (int ii_ = 0; ii_ < 4; ii_++)                                          \
        _Pragma("unroll")                                                        \
        for (int jj_ = 0; jj_ < 2; jj_++)                                        \
          acc[(Mh) * 4 + ii_][(Nh) * 2 + jj_] = __builtin_amdgcn_mfma_f32_16x16x32_bf16( \
              aR[ii_][kk_], bR[jj_][kk_], acc[(Mh) * 4 + ii_][(Nh) * 2 + jj_], 0, 0, 0); \
    __builtin_amdgcn_s_setprio(0);                                               \
  }

#define WAIT6 asm volatile("s_waitcnt vmcnt(6)" ::: "memory")
#define BAR                                                                      \
  {                                                                              \
    asm volatile("" ::: "memory");                                               \
    __builtin_amdgcn_s_barrier();                                                \
    asm volatile("" ::: "memory");                                               \
  }

#define KTILE_BODY(buf, nbuf, tn)                                                \
  {                                                                              \
    /* P1: quadrant (0,0) — needs Ah0[t], Bh0[t] */                              \
    STAGE_A(tn, 0, nbuf);                                                        \
    WAIT6; BAR;                                                                  \
    LOAD_A(buf, 0);                                                              \
    LOAD_B(buf, 0);                                                              \
    MFMA16(0, 0);                                                                \
    BAR;                                                                         \
    /* P2: quadrant (0,1) — needs Bh1[t], reuses aR */                           \
    STAGE_B(tn, 0, nbuf);                                                        \
    WAIT6; BAR;                                                                  \
    LOAD_B(buf, 1);                                                              \
    MFMA16(0, 1);                                                                \
    BAR;                                                                         \
    /* P3: quadrant (1,1) — needs Ah1[t], reuses bR */                           \
    STAGE_B(tn, 1, nbuf);                                                        \
    WAIT6; BAR;                                                                  \
    LOAD_A(buf, 1);                                                              \
    MFMA16(1, 1);                                                                \
    BAR;                                                                         \
    /* P4: quadrant (1,0) — re-reads Bh0[t], reuses aR */                        \
    STAGE_A(tn, 1, nbuf);                                                        \
    WAIT6; BAR;                                                                  \
    LOAD_B(buf, 0);                                                              \
    MFMA16(1, 0);                                                                \
    BAR;                                                                         \
  }

// ================= GEMM 2: attn @ v (per head), round-2 schedule =================
__global__ __launch_bounds__(512, 2)
void k_gemm_attn(const unsigned short* __restrict__ P, const unsigned short* __restrict__ vt,
                 const float* __restrict__ denom, unsigned short* __restrict__ outp) {
  __shared__ unsigned short smem[65536];     // 128 KiB: 2 x (A 256x64 | B 256x64)
  const int K = Tn;
  int tid = threadIdx.x;
  int wave = tid >> 6, lane = tid & 63;
  int wm = wave >> 2, wn = wave & 3;         // per-quadrant: 2x4 waves of 64x32

  int flat = blockIdx.y * 8 + blockIdx.x;    // gridDim = (8, 64)
  int wg = (flat & 7) * 64 + (flat >> 3);    // 64 consecutive tiles per XCD (2 heads)
  int h = wg >> 5;                           // 32 tiles per head (8 M x 4 N)
  int mt = (wg >> 2) & 7, nt = wg & 3;
  int bm = mt * 256, bn = nt * 256;

  const unsigned short* Ap = P + (size_t)h * Tn * Tn;
  const unsigned short* Bp = vt + (size_t)h * (Bn * HDn) * Tn;

  floatx4 zero4 = {0.f, 0.f, 0.f, 0.f};
  floatx4 acc[8][4];
#pragma unroll
  for (int i = 0; i < 8; i++)
#pragma unroll
    for (int j = 0; j < 4; j++) acc[i][j] = zero4;

  short8 aR[4][2], bR[2][2];

  // prologue: stage K-tile 0 into buf0 (same order as steady state)
  STAGE_A(0, 0, 0);
  STAGE_B(0, 0, 0);
  STAGE_B(0, 1, 0);
  STAGE_A(0, 1, 0);

  const int nk = K / 64;                     // 32
  for (int t = 0; t < nk; t++) {
    int buf = t & 1, nbuf = buf ^ 1;
    int tn = (t < nk - 1) ? t + 1 : nk - 1;  // clamp: last iter restages (harmless)
    KTILE_BODY(buf, nbuf, tn);
  }
  asm volatile("s_waitcnt vmcnt(0)" ::: "memory");  // drain before endpgm

  // epilogue: scale by 1/denom, scatter col=(b,d) -> outp[b][row][h*64+d]
#pragma unroll
  for (int i = 0; i < 8; i++) {
    int rb = bm + (i >> 2) * 128 + wm * 64 + (i & 3) * 16 + (lane >> 4) * 4;
#pragma unroll
    for (int r = 0; r < 4; r++) {
      int row = rb + r;
      float sc = 1.f / denom[(size_t)h * Tn + row];
#pragma unroll
      for (int j = 0; j < 4; j++) {
        int col = bn + (j >> 1) * 128 + wn * 32 + (j & 1) * 16 + (lane & 15);
        int b = col >> 6, d = col & 63;
        outp[((size_t)(b * Tn + row)) * En + h * HDn + d] = f2bf(acc[i][j][r] * sc);
      }
    }
  }
}

// ================= GEMM 3: out = o@Wo^T + bo, 256x256 block (round-2 skeleton) =================
__global__ __launch_bounds__(512, 2)
void k_gemm_out(const unsigned short* __restrict__ A, const unsigned short* __restrict__ Bm,
                const float* __restrict__ bias, float* __restrict__ out) {
  __shared__ unsigned short smem[65536];     // 128 KiB
  const int K = 1024, N = 1024;
  int tid = threadIdx.x;
  int wave = tid >> 6, lane = tid & 63;
  int wm = wave >> 2, wn = wave & 3;

  int flat = blockIdx.y * 8 + blockIdx.x;    // gridDim = (8, 64)
  int wg = (flat & 7) * 64 + (flat >> 3);    // 512 blocks: 128 mt x 4 nt
  int mt = wg >> 2, nt = wg & 3;
  int bm = mt * 256, bn = nt * 256;

  const unsigned short* Ap = A;
  const unsigned short* Bp = Bm;

  floatx4 zero4 = {0.f, 0.f, 0.f, 0.f};
  floatx4 acc[8][4];
#pragma unroll
  for (int i = 0; i < 8; i++)
#pragma unroll
    for (int j = 0; j < 4; j++) acc[i][j] = zero4;

  short8 aR[4][2], bR[2][2];

  STAGE_A(0, 0, 0);
  STAGE_B(0, 0, 0);
  STAGE_B(0, 1, 0);
  STAGE_A(0, 1, 0);

  const int nk = K / 64;                     // 16
  for (int t = 0; t < nk; t++) {
    int buf = t & 1, nbuf = buf ^ 1;
    int tn = (t < nk - 1) ? t + 1 : nk - 1;
    KTILE_BODY(buf, nbuf, tn);
  }
  asm volatile("s_waitcnt vmcnt(0)" ::: "memory");

#pragma unroll
  for (int i = 0; i < 8; i++) {
    int rb = bm + (i >> 2) * 128 + wm * 64 + (i & 3) * 16 + (lane >> 4) * 4;
#pragma unroll
    for (int r = 0; r < 4; r++) {
      int row = rb + r;
#pragma unroll
      for (int j = 0; j < 4; j++) {
        int col = bn + (j >> 1) * 128 + wn * 32 + (j & 1) * 16 + (lane & 15);
        out[(size_t)row * N + col] = acc[i][j][r] + bias[col];
      }
    }
  }
}

extern "C" void kernel_launch(void* const* d_in, const int* in_sizes, int n_in,
                              void* d_out, int out_size, void* d_ws, size_t ws_size,
                              hipStream_t stream) {
  const float* x      = (const float*)d_in[0];
  // d_in[1..4] = Wq, bq, Wk, bk — unused by the reference
  const float* Wv     = (const float*)d_in[5];
  const float* bv     = (const float*)d_in[6];
  const float* A_log  = (const float*)d_in[7];
  const float* A_bias = (const float*)d_in[8];
  const float* L      = (const float*)d_in[9];
  const float* Lb     = (const float*)d_in[10];
  const float* Wo     = (const float*)d_in[11];
  const float* bo     = (const float*)d_in[12];
  const int* levels   = (const int*)d_in[13];
  float* out = (float*)d_out;

  // workspace layout (bytes); Pw aliases xb (dead after k_gemm_v)
  char* ws = (char*)d_ws;
  float* csT           = (float*)(ws + 0);                  // 128 KiB (cs, h-major)
  float* denom         = (float*)(ws + 131072);             // 128 KiB
  unsigned short* Wvb  = (unsigned short*)(ws + 262144);    // 2 MiB
  unsigned short* Wob  = (unsigned short*)(ws + 2359296);   // 2 MiB
  unsigned short* xb   = (unsigned short*)(ws + 4456448);   // 64 MiB
  unsigned short* Pw   = (unsigned short*)(ws + 4456448);   // 128 MiB (aliases xb)
  unsigned short* vt   = (unsigned short*)(ws + 138674176); // 64 MiB
  unsigned short* outp = (unsigned short*)(ws + 205783040); // 64 MiB
  if (ws_size < 272891904ULL) return;

  int nx4 = Bn * Tn * En / 4;
  k_cvt<<<(nx4 + 255) / 256, 256, 0, stream>>>(x, xb, nx4);
  int nw4 = En * En / 4;
  k_cvt<<<(nw4 + 255) / 256, 256, 0, stream>>>(Wv, Wvb, nw4);
  k_cvt<<<(nw4 + 255) / 256, 256, 0, stream>>>(Wo, Wob, nw4);
  k_scan<<<NHn, 256, 0, stream>>>(A_log, A_bias, csT);

  k_gemm_v<<<dim3(8, 128), 512, 0, stream>>>(xb, Wvb, bv, vt);

  k_weights<<<Tn, 256, 0, stream>>>(L, Lb, levels, csT, Pw, denom);

  k_gemm_attn<<<dim3(8, 64), 512, 0, stream>>>(Pw, vt, denom, outp);

  k_gemm_out<<<dim3(8, 64), 512, 0, stream>>>(outp, Wob, bo, out);
}

// Round 10
// 572.771 us; speedup vs baseline: 1.2329x; 1.0586x over previous
//
#include <hip/hip_runtime.h>
#include <stdint.h>

static constexpr int Bn = 16, Tn = 2048, En = 1024, NHn = 16, HDn = 64, NLEVn = 12;

typedef __attribute__((ext_vector_type(8))) short short8;
typedef __attribute__((ext_vector_type(4))) float floatx4;

__device__ __forceinline__ unsigned short f2bf(float f) {
  unsigned int u = __float_as_uint(f);
  u += 0x7fffu + ((u >> 16) & 1u);
  return (unsigned short)(u >> 16);
}
__device__ __forceinline__ float bf2f(unsigned short s) {
  return __uint_as_float(((unsigned int)s) << 16);
}

__device__ __forceinline__ void async16(const unsigned short* g, unsigned short* l) {
  __builtin_amdgcn_global_load_lds(
      (const __attribute__((address_space(1))) unsigned int*)g,
      (__attribute__((address_space(3))) unsigned int*)l, 16, 0, 0);
}

// ---------------- fp32 -> bf16 convert ----------------
__global__ void k_cvt(const float* __restrict__ in, unsigned short* __restrict__ out, int n4) {
  int i = blockIdx.x * 256 + threadIdx.x;
  if (i < n4) {
    float4 v = ((const float4*)in)[i];
    ushort4 o;
    o.x = f2bf(v.x); o.y = f2bf(v.y); o.z = f2bf(v.z); o.w = f2bf(v.w);
    ((ushort4*)out)[i] = o;
  }
}

// ---------------- per-head prefix scan of log(sigmoid(A)) -> csT[h][t] ----------------
__global__ void k_scan(const float* __restrict__ A_log, const float* __restrict__ A_bias,
                       float* __restrict__ csT) {
  int h = blockIdx.x;
  int tid = threadIdx.x;
  __shared__ float part[256];
  float loc[8];
  float run = 0.f;
#pragma unroll
  for (int j = 0; j < 8; j++) {
    int t = tid * 8 + j;
    float x = A_log[t * NHn + h] + A_bias[t * NHn + h];
    float ls = -log1pf(__expf(-x));
    run += ls;
    loc[j] = run;
  }
  part[tid] = run;
  __syncthreads();
  for (int d = 1; d < 256; d <<= 1) {
    float v = (tid >= d) ? part[tid - d] : 0.f;
    __syncthreads();
    part[tid] += v;
    __syncthreads();
  }
  float off = (tid > 0) ? part[tid - 1] : 0.f;
#pragma unroll
  for (int j = 0; j < 8; j++) csT[(size_t)h * Tn + tid * 8 + j] = loc[j] + off;
}

// ---------------- unnormalized weights, CAUSAL RANGE ONLY ----------------
// P[h][t][s] for s < Bt = 256*(t/256+1) (the s-range attn's GEMM reads).
// For s in (t, Bt): w = 1.0 (mask writes 0 -> exp = 1). For s >= Bt the value
// is exactly 1.0 and is handled analytically (suffix sum in attn); denom gets
// the exact constant (Tn - Bt) * 1.0 added here.
__global__ void k_weights(const float* __restrict__ L, const float* __restrict__ Lb,
                          const int* __restrict__ levels, const float* __restrict__ csT,
                          unsigned short* __restrict__ P, float* __restrict__ denom) {
  int t = blockIdx.x;
  int tid = threadIdx.x;
  __shared__ float Lrow[NHn * NLEVn];
  __shared__ float cst[NHn];
  __shared__ float dsum[NHn];
  if (tid < NHn * NLEVn) Lrow[tid] = L[t * NHn * NLEVn + tid] + Lb[t * NHn * NLEVn + tid];
  if (tid < NHn) { cst[tid] = csT[(size_t)tid * Tn + t]; dsum[tid] = 0.f; }
  __syncthreads();
  int Bt = ((t >> 8) + 1) << 8;
  float acc[NHn];
#pragma unroll
  for (int h = 0; h < NHn; h++) acc[h] = 0.f;
  for (int s = tid; s < Bt; s += 256) {
    int lev = levels[(size_t)t * Tn + s];
    bool causal = (s <= t);
#pragma unroll
    for (int h = 0; h < NHn; h++) {
      float w = 1.f;   // exp(0) for s > t
      if (causal) {
        float csr = csT[(size_t)h * Tn + s];      // coalesced: 4 B/lane
        float dec = __expf(cst[h] - csr);
        w = __expf(Lrow[h * NLEVn + lev] * dec);
      }
      unsigned short pb = f2bf(w);
      acc[h] += bf2f(pb);
      P[((size_t)h * Tn + t) * Tn + s] = pb;
    }
  }
  int lane = tid & 63;
#pragma unroll
  for (int h = 0; h < NHn; h++) {
    float v = acc[h];
    for (int o = 32; o > 0; o >>= 1) v += __shfl_down(v, o, 64);
    if (lane == 0) atomicAdd(&dsum[h], v);
  }
  __syncthreads();
  if (tid < NHn) denom[(size_t)tid * Tn + t] = dsum[tid] + (float)(Tn - Bt);
}

// ---------------- suffix sums of v: Stail[h][mt][col] = sum_{s>=256(mt+1)} v ----------------
// One 256-thread block per (h,col) row of vt; fp32 sums of bf16 values (same
// rounding as the MFMA path 1.0*bf16(v) would produce).
__global__ void k_tail(const unsigned short* __restrict__ vt, float* __restrict__ Stail) {
  int row = blockIdx.x;            // h*1024 + col, col=(b<<6)|d
  int tid = threadIdx.x;
  __shared__ float C[8];
  short8 v = *(const short8*)&vt[(size_t)row * Tn + tid * 8];
  float p = 0.f;
#pragma unroll
  for (int e = 0; e < 8; e++) p += bf2f((unsigned short)v[e]);
  // reduce within each 32-thread chunk (chunk = 256 consecutive s)
#pragma unroll
  for (int o = 16; o > 0; o >>= 1) p += __shfl_xor(p, o, 64);
  if ((tid & 31) == 0) C[tid >> 5] = p;
  __syncthreads();
  if (tid < 8) {
    float s = 0.f;
    for (int k = tid + 1; k < 8; k++) s += C[k];
    int h = row >> 10, col = row & 1023;
    Stail[(size_t)h * 8192 + tid * 1024 + col] = s;
  }
}

// ================= GEMM 1: v = x@Wv^T + bv, 256x128 block, fused transpose =================
// (round-0 proven version: 48 KiB LDS, 2 blocks/CU)
__global__ __launch_bounds__(512)
void k_gemm_v(const unsigned short* __restrict__ A, const unsigned short* __restrict__ Bm,
              const float* __restrict__ bias, unsigned short* __restrict__ vt) {
  __shared__ unsigned short smem[24576];     // 48 KB: As(32K) | Bs(16K); epilogue reuses as Ct
  unsigned short* As = smem;                 // 256 x 64
  unsigned short* Bs = smem + 16384;         // 128 x 64
  const int K = 1024;
  int tid = threadIdx.x;
  int wave = tid >> 6, lane = tid & 63;
  int wm = wave >> 1, wn = wave & 1;         // 4 x 2 waves of 64x64 tiles

  int flat = blockIdx.y * 8 + blockIdx.x;    // gridDim.x == 8
  int xcd = flat & 7, slot = flat >> 3;      // slot 0..127
  int strip = xcd * 16 + (slot >> 3);        // 128 strips, 16 per XCD
  int nt = slot & 7;
  int bm = strip * 256, bn = nt * 128;

  floatx4 zero4 = {0.f, 0.f, 0.f, 0.f};
  floatx4 acc[4][4];
#pragma unroll
  for (int i = 0; i < 4; i++)
#pragma unroll
    for (int j = 0; j < 4; j++) acc[i][j] = zero4;

  for (int k0 = 0; k0 < K; k0 += 64) {
    __syncthreads();
#pragma unroll
    for (int j = 0; j < 4; j++) {            // A: 256 rows x 64 k (32KB)
      int f = j * 512 + tid;
      int r = f >> 3, c = f & 7;
      int cg = c ^ (r & 7);
      async16(&A[(size_t)(bm + r) * K + k0 + cg * 8], &As[f * 8]);
    }
#pragma unroll
    for (int j = 0; j < 2; j++) {            // B: 128 rows x 64 k (16KB)
      int f = j * 512 + tid;
      int r = f >> 3, c = f & 7;
      int cg = c ^ (r & 7);
      async16(&Bm[(size_t)(bn + r) * K + k0 + cg * 8], &Bs[f * 8]);
    }
    __syncthreads();
#pragma unroll
    for (int kk = 0; kk < 2; kk++) {
      short8 af[4], bfr[4];
      int cgk = kk * 4 + (lane >> 4);
#pragma unroll
      for (int i = 0; i < 4; i++) {
        int m = wm * 64 + i * 16 + (lane & 15);
        af[i] = *(const short8*)&As[m * 64 + ((cgk ^ (m & 7)) * 8)];
        int n = wn * 64 + i * 16 + (lane & 15);
        bfr[i] = *(const short8*)&Bs[n * 64 + ((cgk ^ (n & 7)) * 8)];
      }
#pragma unroll
      for (int i = 0; i < 4; i++)
#pragma unroll
        for (int j = 0; j < 4; j++)
          acc[i][j] = __builtin_amdgcn_mfma_f32_16x16x32_bf16(af[i], bfr[j], acc[i][j], 0, 0, 0);
    }
  }

  // ---- fused transpose epilogue: write vt[h][b][d][t] ----
  int b = bm >> 11, t0 = bm & 2047;
  unsigned short* Ct = smem;                 // 64 cols x (256+8) rows
  const int S = 264;
#pragma unroll 1
  for (int pass = 0; pass < 2; pass++) {
    __syncthreads();
    if (wn == pass) {
#pragma unroll
      for (int i = 0; i < 4; i++) {
#pragma unroll
        for (int j = 0; j < 4; j++) {
          int colL = j * 16 + (lane & 15);
          float bia = bias[bn + pass * 64 + colL];
          int rowb = wm * 64 + i * 16 + (lane >> 4) * 4;
          ushort4 p;
          p.x = f2bf(acc[i][j][0] + bia);
          p.y = f2bf(acc[i][j][1] + bia);
          p.z = f2bf(acc[i][j][2] + bia);
          p.w = f2bf(acc[i][j][3] + bia);
          *(ushort4*)&Ct[colL * S + rowb] = p;
        }
      }
    }
    __syncthreads();
#pragma unroll
    for (int cc = 0; cc < 4; cc++) {
      int colL = wave * 8 + cc * 2 + (lane >> 5);
      int gc = bn + pass * 64 + colL;
      int h = gc >> 6, d = gc & 63;
      int tt = (lane & 31) * 8;
      short8 v = *(const short8*)&Ct[colL * S + tt];
      *(short8*)&vt[((size_t)((h * Bn + b) * HDn + d)) * Tn + t0 + tt] = v;
    }
  }
}

// ================= shared 256x256 BK=64 macros (round-2 verified) =================

#define STAGE_A(kt, half, buf)                                                   \
  {                                                                              \
    _Pragma("unroll")                                                            \
    for (int j_ = 0; j_ < 2; j_++) {                                             \
      int f_ = j_ * 512 + tid;                                                   \
      int r_ = f_ >> 3, c_ = f_ & 7;                                             \
      int cg_ = c_ ^ (r_ & 7);                                                   \
      async16(&Ap[(size_t)(bm + (half) * 128 + r_) * K + (kt) * 64 + cg_ * 8],   \
              &smem[(buf) * 32768 + ((half) * 128 + r_) * 64 + c_ * 8]);         \
    }                                                                            \
  }

#define STAGE_B(kt, half, buf)                                                   \
  {                                                                              \
    _Pragma("unroll")                                                            \
    for (int j_ = 0; j_ < 2; j_++) {                                             \
      int f_ = j_ * 512 + tid;                                                   \
      int r_ = f_ >> 3, c_ = f_ & 7;                                             \
      int cg_ = c_ ^ (r_ & 7);                                                   \
      async16(&Bp[(size_t)(bn + (half) * 128 + r_) * K + (kt) * 64 + cg_ * 8],   \
              &smem[(buf) * 32768 + 16384 + ((half) * 128 + r_) * 64 + c_ * 8]); \
    }                                                                            \
  }

#define LOAD_A(buf, Mh)                                                          \
  {                                                                              \
    _Pragma("unroll")                                                            \
    for (int ii_ = 0; ii_ < 4; ii_++) {                                          \
      int m_ = (Mh) * 128 + wm * 64 + ii_ * 16 + (lane & 15);                    \
      _Pragma("unroll")                                                          \
      for (int kk_ = 0; kk_ < 2; kk_++) {                                        \
        int cgk_ = kk_ * 4 + (lane >> 4);                                        \
        aR[ii_][kk_] =                                                           \
            *(const short8*)&smem[(buf) * 32768 + m_ * 64 + ((cgk_ ^ (m_ & 7)) * 8)]; \
      }                                                                          \
    }                                                                            \
  }

#define LOAD_B(buf, Nh)                                                          \
  {                                                                              \
    _Pragma("unroll")                                                            \
    for (int jj_ = 0; jj_ < 2; jj_++) {                                          \
      int n_ = (Nh) * 128 + wn * 32 + jj_ * 16 + (lane & 15);                    \
      _Pragma("unroll")                                                          \
      for (int kk_ = 0; kk_ < 2; kk_++) {                                        \
        int cgk_ = kk_ * 4 + (lane >> 4);                                        \
        bR[jj_][kk_] = *(const short8*)&smem[(buf) * 32768 + 16384 + n_ * 64 +   \
                                             ((cgk_ ^ (n_ & 7)) * 8)];           \
      }                                                                          \
    }                                                                            \
  }

#define MFMA16(Mh, Nh)                                                           \
  {                                                                              \
    __builtin_amdgcn_s_setprio(1);                                               \
    _Pragma("unroll")                                                            \
    for (int kk_ = 0; kk_ < 2; kk_++)                                            \
      _Pragma("unroll")                                                          \
      for (int ii_ = 0; ii_ < 4; ii_++)                                          \
        _Pragma("unroll")                                                        \
        for (int jj_ = 0; jj_ < 2; jj_++)                                        \
          acc[(Mh) * 4 + ii_][(Nh) * 2 + jj_] = __builtin_amdgcn_mfma_f32_16x16x32_bf16( \
              aR[ii_][kk_], bR[jj_][kk_], acc[(Mh) * 4 + ii_][(Nh) * 2 + jj_], 0, 0, 0); \
    __builtin_amdgcn_s_setprio(0);                                               \
  }

#define WAIT6 asm volatile("s_waitcnt vmcnt(6)" ::: "memory")
#define BAR                                                                      \
  {                                                                              \
    asm volatile("" ::: "memory");                                               \
    __builtin_amdgcn_s_barrier();                                                \
    asm volatile("" ::: "memory");                                               \
  }

#define KTILE_BODY(buf, nbuf, tn)                                                \
  {                                                                              \
    /* P1: quadrant (0,0) — needs Ah0[t], Bh0[t] */                              \
    STAGE_A(tn, 0, nbuf);                                                        \
    WAIT6; BAR;                                                                  \
    LOAD_A(buf, 0);                                                              \
    LOAD_B(buf, 0);                                                              \
    MFMA16(0, 0);                                                                \
    BAR;                                                                         \
    /* P2: quadrant (0,1) — needs Bh1[t], reuses aR */                           \
    STAGE_B(tn, 0, nbuf);                                                        \
    WAIT6; BAR;                                                                  \
    LOAD_B(buf, 1);                                                              \
    MFMA16(0, 1);                                                                \
    BAR;                                                                         \
    /* P3: quadrant (1,1) — needs Ah1[t], reuses bR */                           \
    STAGE_B(tn, 1, nbuf);                                                        \
    WAIT6; BAR;                                                                  \
    LOAD_A(buf, 1);                                                              \
    MFMA16(1, 1);                                                                \
    BAR;                                                                         \
    /* P4: quadrant (1,0) — re-reads Bh0[t], reuses aR */                        \
    STAGE_A(tn, 1, nbuf);                                                        \
    WAIT6; BAR;                                                                  \
    LOAD_B(buf, 0);                                                              \
    MFMA16(1, 0);                                                                \
    BAR;                                                                         \
  }

// ================= GEMM 2: attn @ v (per head), causal-range K-loop =================
// Row-block mt only iterates K-tiles s < 256*(mt+1); the all-ones region
// s >= 256*(mt+1) is added analytically via Stail (suffix sums of v).
__global__ __launch_bounds__(512, 2)
void k_gemm_attn(const unsigned short* __restrict__ P, const unsigned short* __restrict__ vt,
                 const float* __restrict__ denom, const float* __restrict__ Stail,
                 unsigned short* __restrict__ outp) {
  __shared__ unsigned short smem[65536];     // 128 KiB: 2 x (A 256x64 | B 256x64)
  const int K = Tn;
  int tid = threadIdx.x;
  int wave = tid >> 6, lane = tid & 63;
  int wm = wave >> 2, wn = wave & 3;         // per-quadrant: 2x4 waves of 64x32

  int flat = blockIdx.y * 8 + blockIdx.x;    // gridDim = (8, 64)
  int wg = (flat & 7) * 64 + (flat >> 3);    // 64 consecutive tiles per XCD (2 heads)
  int h = wg >> 5;                           // 32 tiles per head (8 M x 4 N)
  int mt = (wg >> 2) & 7, nt = wg & 3;
  int bm = mt * 256, bn = nt * 256;

  const unsigned short* Ap = P + (size_t)h * Tn * Tn;
  const unsigned short* Bp = vt + (size_t)h * (Bn * HDn) * Tn;

  floatx4 zero4 = {0.f, 0.f, 0.f, 0.f};
  floatx4 acc[8][4];
#pragma unroll
  for (int i = 0; i < 8; i++)
#pragma unroll
    for (int j = 0; j < 4; j++) acc[i][j] = zero4;

  short8 aR[4][2], bR[2][2];

  // prologue: stage K-tile 0 into buf0 (same order as steady state)
  STAGE_A(0, 0, 0);
  STAGE_B(0, 0, 0);
  STAGE_B(0, 1, 0);
  STAGE_A(0, 1, 0);

  const int nkb = 4 * (mt + 1);              // causal K-tiles only (s < 256*(mt+1))
  for (int t = 0; t < nkb; t++) {
    int buf = t & 1, nbuf = buf ^ 1;
    int tn = (t < nkb - 1) ? t + 1 : nkb - 1;  // clamp: last iter restages (harmless)
    KTILE_BODY(buf, nbuf, tn);
  }
  asm volatile("s_waitcnt vmcnt(0)" ::: "memory");  // drain before endpgm

  // tail: per-column suffix sum of v over s >= 256*(mt+1)
  float tl[4];
#pragma unroll
  for (int j = 0; j < 4; j++) {
    int col = bn + (j >> 1) * 128 + wn * 32 + (j & 1) * 16 + (lane & 15);
    tl[j] = Stail[(size_t)h * 8192 + mt * 1024 + col];
  }

  // epilogue: (acc + tail) / denom, scatter col=(b,d) -> outp[b][row][h*64+d]
#pragma unroll
  for (int i = 0; i < 8; i++) {
    int rb = bm + (i >> 2) * 128 + wm * 64 + (i & 3) * 16 + (lane >> 4) * 4;
#pragma unroll
    for (int r = 0; r < 4; r++) {
      int row = rb + r;
      float sc = 1.f / denom[(size_t)h * Tn + row];
#pragma unroll
      for (int j = 0; j < 4; j++) {
        int col = bn + (j >> 1) * 128 + wn * 32 + (j & 1) * 16 + (lane & 15);
        int b = col >> 6, d = col & 63;
        outp[((size_t)(b * Tn + row)) * En + h * HDn + d] = f2bf((acc[i][j][r] + tl[j]) * sc);
      }
    }
  }
}

// ================= GEMM 3: out = o@Wo^T + bo, 256x256 block (round-2 skeleton) =================
__global__ __launch_bounds__(512, 2)
void k_gemm_out(const unsigned short* __restrict__ A, const unsigned short* __restrict__ Bm,
                const float* __restrict__ bias, float* __restrict__ out) {
  __shared__ unsigned short smem[65536];     // 128 KiB
  const int K = 1024, N = 1024;
  int tid = threadIdx.x;
  int wave = tid >> 6, lane = tid & 63;
  int wm = wave >> 2, wn = wave & 3;

  int flat = blockIdx.y * 8 + blockIdx.x;    // gridDim = (8, 64)
  int wg = (flat & 7) * 64 + (flat >> 3);    // 512 blocks: 128 mt x 4 nt
  int mt = wg >> 2, nt = wg & 3;
  int bm = mt * 256, bn = nt * 256;

  const unsigned short* Ap = A;
  const unsigned short* Bp = Bm;

  floatx4 zero4 = {0.f, 0.f, 0.f, 0.f};
  floatx4 acc[8][4];
#pragma unroll
  for (int i = 0; i < 8; i++)
#pragma unroll
    for (int j = 0; j < 4; j++) acc[i][j] = zero4;

  short8 aR[4][2], bR[2][2];

  STAGE_A(0, 0, 0);
  STAGE_B(0, 0, 0);
  STAGE_B(0, 1, 0);
  STAGE_A(0, 1, 0);

  const int nk = K / 64;                     // 16
  for (int t = 0; t < nk; t++) {
    int buf = t & 1, nbuf = buf ^ 1;
    int tn = (t < nk - 1) ? t + 1 : nk - 1;
    KTILE_BODY(buf, nbuf, tn);
  }
  asm volatile("s_waitcnt vmcnt(0)" ::: "memory");

#pragma unroll
  for (int i = 0; i < 8; i++) {
    int rb = bm + (i >> 2) * 128 + wm * 64 + (i & 3) * 16 + (lane >> 4) * 4;
#pragma unroll
    for (int r = 0; r < 4; r++) {
      int row = rb + r;
#pragma unroll
      for (int j = 0; j < 4; j++) {
        int col = bn + (j >> 1) * 128 + wn * 32 + (j & 1) * 16 + (lane & 15);
        out[(size_t)row * N + col] = acc[i][j][r] + bias[col];
      }
    }
  }
}

extern "C" void kernel_launch(void* const* d_in, const int* in_sizes, int n_in,
                              void* d_out, int out_size, void* d_ws, size_t ws_size,
                              hipStream_t stream) {
  const float* x      = (const float*)d_in[0];
  // d_in[1..4] = Wq, bq, Wk, bk — unused by the reference
  const float* Wv     = (const float*)d_in[5];
  const float* bv     = (const float*)d_in[6];
  const float* A_log  = (const float*)d_in[7];
  const float* A_bias = (const float*)d_in[8];
  const float* L      = (const float*)d_in[9];
  const float* Lb     = (const float*)d_in[10];
  const float* Wo     = (const float*)d_in[11];
  const float* bo     = (const float*)d_in[12];
  const int* levels   = (const int*)d_in[13];
  float* out = (float*)d_out;

  // workspace layout (bytes); Pw aliases xb (dead after k_gemm_v)
  char* ws = (char*)d_ws;
  float* csT           = (float*)(ws + 0);                  // 128 KiB (cs, h-major)
  float* denom         = (float*)(ws + 131072);             // 128 KiB
  unsigned short* Wvb  = (unsigned short*)(ws + 262144);    // 2 MiB
  unsigned short* Wob  = (unsigned short*)(ws + 2359296);   // 2 MiB
  unsigned short* xb   = (unsigned short*)(ws + 4456448);   // 64 MiB
  unsigned short* Pw   = (unsigned short*)(ws + 4456448);   // 128 MiB (aliases xb)
  unsigned short* vt   = (unsigned short*)(ws + 138674176); // 64 MiB
  unsigned short* outp = (unsigned short*)(ws + 205783040); // 64 MiB
  if (ws_size < 272891904ULL) return;

  // Stail scratch lives in the tail of d_out (512 KiB); gemm_out overwrites it
  // at the end, and the stream order k_tail -> k_gemm_attn -> k_gemm_out makes
  // the aliasing safe.
  float* Stail = out + (33554432 - 131072);  // out has 33,554,432 floats

  int nx4 = Bn * Tn * En / 4;
  k_cvt<<<(nx4 + 255) / 256, 256, 0, stream>>>(x, xb, nx4);
  int nw4 = En * En / 4;
  k_cvt<<<(nw4 + 255) / 256, 256, 0, stream>>>(Wv, Wvb, nw4);
  k_cvt<<<(nw4 + 255) / 256, 256, 0, stream>>>(Wo, Wob, nw4);
  k_scan<<<NHn, 256, 0, stream>>>(A_log, A_bias, csT);

  k_gemm_v<<<dim3(8, 128), 512, 0, stream>>>(xb, Wvb, bv, vt);

  k_tail<<<NHn * 1024, 256, 0, stream>>>(vt, Stail);

  k_weights<<<Tn, 256, 0, stream>>>(L, Lb, levels, csT, Pw, denom);

  k_gemm_attn<<<dim3(8, 64), 512, 0, stream>>>(Pw, vt, denom, Stail, outp);

  k_gemm_out<<<dim3(8, 64), 512, 0, stream>>>(outp, Wob, bo, out);
}

// Round 11
// 543.563 us; speedup vs baseline: 1.2992x; 1.0537x over previous
//
#include <hip/hip_runtime.h>
#include <stdint.h>

static constexpr int Bn = 16, Tn = 2048, En = 1024, NHn = 16, HDn = 64, NLEVn = 12;

typedef __attribute__((ext_vector_type(8))) short short8;
typedef __attribute__((ext_vector_type(4))) float floatx4;

__device__ __forceinline__ unsigned short f2bf(float f) {
  unsigned int u = __float_as_uint(f);
  u += 0x7fffu + ((u >> 16) & 1u);
  return (unsigned short)(u >> 16);
}
__device__ __forceinline__ float bf2f(unsigned short s) {
  return __uint_as_float(((unsigned int)s) << 16);
}

__device__ __forceinline__ void async16(const unsigned short* g, unsigned short* l) {
  __builtin_amdgcn_global_load_lds(
      (const __attribute__((address_space(1))) unsigned int*)g,
      (__attribute__((address_space(3))) unsigned int*)l, 16, 0, 0);
}

// ---------------- fp32 -> bf16 convert ----------------
__global__ void k_cvt(const float* __restrict__ in, unsigned short* __restrict__ out, int n4) {
  int i = blockIdx.x * 256 + threadIdx.x;
  if (i < n4) {
    float4 v = ((const float4*)in)[i];
    ushort4 o;
    o.x = f2bf(v.x); o.y = f2bf(v.y); o.z = f2bf(v.z); o.w = f2bf(v.w);
    ((ushort4*)out)[i] = o;
  }
}

// ---------------- per-head prefix scan of log(sigmoid(A)) -> csT[h][t] ----------------
__global__ void k_scan(const float* __restrict__ A_log, const float* __restrict__ A_bias,
                       float* __restrict__ csT) {
  int h = blockIdx.x;
  int tid = threadIdx.x;
  __shared__ float part[256];
  float loc[8];
  float run = 0.f;
#pragma unroll
  for (int j = 0; j < 8; j++) {
    int t = tid * 8 + j;
    float x = A_log[t * NHn + h] + A_bias[t * NHn + h];
    float ls = -log1pf(__expf(-x));
    run += ls;
    loc[j] = run;
  }
  part[tid] = run;
  __syncthreads();
  for (int d = 1; d < 256; d <<= 1) {
    float v = (tid >= d) ? part[tid - d] : 0.f;
    __syncthreads();
    part[tid] += v;
    __syncthreads();
  }
  float off = (tid > 0) ? part[tid - 1] : 0.f;
#pragma unroll
  for (int j = 0; j < 8; j++) csT[(size_t)h * Tn + tid * 8 + j] = loc[j] + off;
}

// ---------------- unnormalized weights, CAUSAL RANGE ONLY ----------------
// P[h][t][s] for s < Bt = 256*(t/256+1) (the s-range attn's GEMM reads).
// For s in (t, Bt): w = 1.0 (mask writes 0 -> exp = 1). For s >= Bt the value
// is exactly 1.0 and is handled analytically (suffix sum in attn); denom gets
// the exact constant (Tn - Bt) * 1.0 added here.
__global__ void k_weights(const float* __restrict__ L, const float* __restrict__ Lb,
                          const int* __restrict__ levels, const float* __restrict__ csT,
                          unsigned short* __restrict__ P, float* __restrict__ denom) {
  int t = blockIdx.x;
  int tid = threadIdx.x;
  __shared__ float Lrow[NHn * NLEVn];
  __shared__ float cst[NHn];
  __shared__ float dsum[NHn];
  if (tid < NHn * NLEVn) Lrow[tid] = L[t * NHn * NLEVn + tid] + Lb[t * NHn * NLEVn + tid];
  if (tid < NHn) { cst[tid] = csT[(size_t)tid * Tn + t]; dsum[tid] = 0.f; }
  __syncthreads();
  int Bt = ((t >> 8) + 1) << 8;
  float acc[NHn];
#pragma unroll
  for (int h = 0; h < NHn; h++) acc[h] = 0.f;
  for (int s = tid; s < Bt; s += 256) {
    int lev = levels[(size_t)t * Tn + s];
    bool causal = (s <= t);
#pragma unroll
    for (int h = 0; h < NHn; h++) {
      float w = 1.f;   // exp(0) for s > t
      if (causal) {
        float csr = csT[(size_t)h * Tn + s];      // coalesced: 4 B/lane
        float dec = __expf(cst[h] - csr);
        w = __expf(Lrow[h * NLEVn + lev] * dec);
      }
      unsigned short pb = f2bf(w);
      acc[h] += bf2f(pb);
      P[((size_t)h * Tn + t) * Tn + s] = pb;
    }
  }
  int lane = tid & 63;
#pragma unroll
  for (int h = 0; h < NHn; h++) {
    float v = acc[h];
    for (int o = 32; o > 0; o >>= 1) v += __shfl_down(v, o, 64);
    if (lane == 0) atomicAdd(&dsum[h], v);
  }
  __syncthreads();
  if (tid < NHn) denom[(size_t)tid * Tn + t] = dsum[tid] + (float)(Tn - Bt);
}

// ---------------- suffix sums of v: Stail[h][mt][col] = sum_{s>=256(mt+1)} v ----------------
__global__ void k_tail(const unsigned short* __restrict__ vt, float* __restrict__ Stail) {
  int row = blockIdx.x;            // h*1024 + col, col=(b<<6)|d
  int tid = threadIdx.x;
  __shared__ float C[8];
  short8 v = *(const short8*)&vt[(size_t)row * Tn + tid * 8];
  float p = 0.f;
#pragma unroll
  for (int e = 0; e < 8; e++) p += bf2f((unsigned short)v[e]);
#pragma unroll
  for (int o = 16; o > 0; o >>= 1) p += __shfl_xor(p, o, 64);
  if ((tid & 31) == 0) C[tid >> 5] = p;
  __syncthreads();
  if (tid < 8) {
    float s = 0.f;
    for (int k = tid + 1; k < 8; k++) s += C[k];
    int h = row >> 10, col = row & 1023;
    Stail[(size_t)h * 8192 + tid * 1024 + col] = s;
  }
}

// ================= GEMM 1: v = x@Wv^T + bv, 256x128 block, fused transpose =================
// (round-0 proven version: 48 KiB LDS, 2 blocks/CU)
__global__ __launch_bounds__(512)
void k_gemm_v(const unsigned short* __restrict__ A, const unsigned short* __restrict__ Bm,
              const float* __restrict__ bias, unsigned short* __restrict__ vt) {
  __shared__ unsigned short smem[24576];     // 48 KB: As(32K) | Bs(16K); epilogue reuses as Ct
  unsigned short* As = smem;                 // 256 x 64
  unsigned short* Bs = smem + 16384;         // 128 x 64
  const int K = 1024;
  int tid = threadIdx.x;
  int wave = tid >> 6, lane = tid & 63;
  int wm = wave >> 1, wn = wave & 1;         // 4 x 2 waves of 64x64 tiles

  int flat = blockIdx.y * 8 + blockIdx.x;    // gridDim.x == 8
  int xcd = flat & 7, slot = flat >> 3;      // slot 0..127
  int strip = xcd * 16 + (slot >> 3);        // 128 strips, 16 per XCD
  int nt = slot & 7;
  int bm = strip * 256, bn = nt * 128;

  floatx4 zero4 = {0.f, 0.f, 0.f, 0.f};
  floatx4 acc[4][4];
#pragma unroll
  for (int i = 0; i < 4; i++)
#pragma unroll
    for (int j = 0; j < 4; j++) acc[i][j] = zero4;

  for (int k0 = 0; k0 < K; k0 += 64) {
    __syncthreads();
#pragma unroll
    for (int j = 0; j < 4; j++) {            // A: 256 rows x 64 k (32KB)
      int f = j * 512 + tid;
      int r = f >> 3, c = f & 7;
      int cg = c ^ (r & 7);
      async16(&A[(size_t)(bm + r) * K + k0 + cg * 8], &As[f * 8]);
    }
#pragma unroll
    for (int j = 0; j < 2; j++) {            // B: 128 rows x 64 k (16KB)
      int f = j * 512 + tid;
      int r = f >> 3, c = f & 7;
      int cg = c ^ (r & 7);
      async16(&Bm[(size_t)(bn + r) * K + k0 + cg * 8], &Bs[f * 8]);
    }
    __syncthreads();
#pragma unroll
    for (int kk = 0; kk < 2; kk++) {
      short8 af[4], bfr[4];
      int cgk = kk * 4 + (lane >> 4);
#pragma unroll
      for (int i = 0; i < 4; i++) {
        int m = wm * 64 + i * 16 + (lane & 15);
        af[i] = *(const short8*)&As[m * 64 + ((cgk ^ (m & 7)) * 8)];
        int n = wn * 64 + i * 16 + (lane & 15);
        bfr[i] = *(const short8*)&Bs[n * 64 + ((cgk ^ (n & 7)) * 8)];
      }
#pragma unroll
      for (int i = 0; i < 4; i++)
#pragma unroll
        for (int j = 0; j < 4; j++)
          acc[i][j] = __builtin_amdgcn_mfma_f32_16x16x32_bf16(af[i], bfr[j], acc[i][j], 0, 0, 0);
    }
  }

  // ---- fused transpose epilogue: write vt[h][b][d][t] ----
  int b = bm >> 11, t0 = bm & 2047;
  unsigned short* Ct = smem;                 // 64 cols x (256+8) rows
  const int S = 264;
#pragma unroll 1
  for (int pass = 0; pass < 2; pass++) {
    __syncthreads();
    if (wn == pass) {
#pragma unroll
      for (int i = 0; i < 4; i++) {
#pragma unroll
        for (int j = 0; j < 4; j++) {
          int colL = j * 16 + (lane & 15);
          float bia = bias[bn + pass * 64 + colL];
          int rowb = wm * 64 + i * 16 + (lane >> 4) * 4;
          ushort4 p;
          p.x = f2bf(acc[i][j][0] + bia);
          p.y = f2bf(acc[i][j][1] + bia);
          p.z = f2bf(acc[i][j][2] + bia);
          p.w = f2bf(acc[i][j][3] + bia);
          *(ushort4*)&Ct[colL * S + rowb] = p;
        }
      }
    }
    __syncthreads();
#pragma unroll
    for (int cc = 0; cc < 4; cc++) {
      int colL = wave * 8 + cc * 2 + (lane >> 5);
      int gc = bn + pass * 64 + colL;
      int h = gc >> 6, d = gc & 63;
      int tt = (lane & 31) * 8;
      short8 v = *(const short8*)&Ct[colL * S + tt];
      *(short8*)&vt[((size_t)((h * Bn + b) * HDn + d)) * Tn + t0 + tt] = v;
    }
  }
}

// ================= shared 256x256 BK=64 macros (round-2 verified) =================

#define STAGE_A(kt, half, buf)                                                   \
  {                                                                              \
    _Pragma("unroll")                                                            \
    for (int j_ = 0; j_ < 2; j_++) {                                             \
      int f_ = j_ * 512 + tid;                                                   \
      int r_ = f_ >> 3, c_ = f_ & 7;                                             \
      int cg_ = c_ ^ (r_ & 7);                                                   \
      async16(&Ap[(size_t)(bm + (half) * 128 + r_) * K + (kt) * 64 + cg_ * 8],   \
              &smem[(buf) * 32768 + ((half) * 128 + r_) * 64 + c_ * 8]);         \
    }                                                                            \
  }

#define STAGE_B(kt, half, buf)                                                   \
  {                                                                              \
    _Pragma("unroll")                                                            \
    for (int j_ = 0; j_ < 2; j_++) {                                             \
      int f_ = j_ * 512 + tid;                                                   \
      int r_ = f_ >> 3, c_ = f_ & 7;                                             \
      int cg_ = c_ ^ (r_ & 7);                                                   \
      async16(&Bp[(size_t)(bn + (half) * 128 + r_) * K + (kt) * 64 + cg_ * 8],   \
              &smem[(buf) * 32768 + 16384 + ((half) * 128 + r_) * 64 + c_ * 8]); \
    }                                                                            \
  }

#define LOAD_A(buf, Mh)                                                          \
  {                                                                              \
    _Pragma("unroll")                                                            \
    for (int ii_ = 0; ii_ < 4; ii_++) {                                          \
      int m_ = (Mh) * 128 + wm * 64 + ii_ * 16 + (lane & 15);                    \
      _Pragma("unroll")                                                          \
      for (int kk_ = 0; kk_ < 2; kk_++) {                                        \
        int cgk_ = kk_ * 4 + (lane >> 4);                                        \
        aR[ii_][kk_] =                                                           \
            *(const short8*)&smem[(buf) * 32768 + m_ * 64 + ((cgk_ ^ (m_ & 7)) * 8)]; \
      }                                                                          \
    }                                                                            \
  }

#define LOAD_B(buf, Nh)                                                          \
  {                                                                              \
    _Pragma("unroll")                                                            \
    for (int jj_ = 0; jj_ < 2; jj_++) {                                          \
      int n_ = (Nh) * 128 + wn * 32 + jj_ * 16 + (lane & 15);                    \
      _Pragma("unroll")                                                          \
      for (int kk_ = 0; kk_ < 2; kk_++) {                                        \
        int cgk_ = kk_ * 4 + (lane >> 4);                                        \
        bR[jj_][kk_] = *(const short8*)&smem[(buf) * 32768 + 16384 + n_ * 64 +   \
                                             ((cgk_ ^ (n_ & 7)) * 8)];           \
      }                                                                          \
    }                                                                            \
  }

#define MFMA16(Mh, Nh)                                                           \
  {                                                                              \
    __builtin_amdgcn_s_setprio(1);                                               \
    _Pragma("unroll")                                                            \
    for (int kk_ = 0; kk_ < 2; kk_++)                                            \
      _Pragma("unroll")                                                          \
      for (int ii_ = 0; ii_ < 4; ii_++)                                          \
        _Pragma("unroll")                                                        \
        for (int jj_ = 0; jj_ < 2; jj_++)                                        \
          acc[(Mh) * 4 + ii_][(Nh) * 2 + jj_] = __builtin_amdgcn_mfma_f32_16x16x32_bf16( \
              aR[ii_][kk_], bR[jj_][kk_], acc[(Mh) * 4 + ii_][(Nh) * 2 + jj_], 0, 0, 0); \
    __builtin_amdgcn_s_setprio(0);                                               \
  }

#define WAIT6 asm volatile("s_waitcnt vmcnt(6)" ::: "memory")
#define BAR                                                                      \
  {                                                                              \
    asm volatile("" ::: "memory");                                               \
    __builtin_amdgcn_s_barrier();                                                \
    asm volatile("" ::: "memory");                                               \
  }

#define KTILE_BODY(buf, nbuf, tn)                                                \
  {                                                                              \
    /* P1: quadrant (0,0) — needs Ah0[t], Bh0[t] */                              \
    STAGE_A(tn, 0, nbuf);                                                        \
    WAIT6; BAR;                                                                  \
    LOAD_A(buf, 0);                                                              \
    LOAD_B(buf, 0);                                                              \
    MFMA16(0, 0);                                                                \
    BAR;                                                                         \
    /* P2: quadrant (0,1) — needs Bh1[t], reuses aR */                           \
    STAGE_B(tn, 0, nbuf);                                                        \
    WAIT6; BAR;                                                                  \
    LOAD_B(buf, 1);                                                              \
    MFMA16(0, 1);                                                                \
    BAR;                                                                         \
    /* P3: quadrant (1,1) — needs Ah1[t], reuses bR */                           \
    STAGE_B(tn, 1, nbuf);                                                        \
    WAIT6; BAR;                                                                  \
    LOAD_A(buf, 1);                                                              \
    MFMA16(1, 1);                                                                \
    BAR;                                                                         \
    /* P4: quadrant (1,0) — re-reads Bh0[t], reuses aR */                        \
    STAGE_A(tn, 1, nbuf);                                                        \
    WAIT6; BAR;                                                                  \
    LOAD_B(buf, 0);                                                              \
    MFMA16(1, 0);                                                                \
    BAR;                                                                         \
  }

// ================= GEMM 2: attn @ v (per head), causal-range K-loop =================
// Work per block = 4*(mt+1) K-tiles. Complementary-mt pairing: a CU inside an
// XCD runs slots y and y+32 sequentially; flipping mt -> 7-mt for the upper
// half makes each CU's pair cost 4(mt+1)+4(8-mt) = 36 tiles, uniform.
__global__ __launch_bounds__(512, 2)
void k_gemm_attn(const unsigned short* __restrict__ P, const unsigned short* __restrict__ vt,
                 const float* __restrict__ denom, const float* __restrict__ Stail,
                 unsigned short* __restrict__ outp) {
  __shared__ unsigned short smem[65536];     // 128 KiB: 2 x (A 256x64 | B 256x64)
  const int K = Tn;
  int tid = threadIdx.x;
  int wave = tid >> 6, lane = tid & 63;
  int wm = wave >> 2, wn = wave & 3;         // per-quadrant: 2x4 waves of 64x32

  int flat = blockIdx.y * 8 + blockIdx.x;    // gridDim = (8, 64)
  int xcd = flat & 7, slot = flat >> 3;      // slot 0..63 within XCD
  int h = xcd * 2 + (slot >> 5);             // 2 heads per XCD
  int mtraw = (slot >> 2) & 7;
  int mt = (slot & 32) ? (7 - mtraw) : mtraw;  // complementary-mt pairing
  int nt = slot & 3;
  int bm = mt * 256, bn = nt * 256;

  const unsigned short* Ap = P + (size_t)h * Tn * Tn;
  const unsigned short* Bp = vt + (size_t)h * (Bn * HDn) * Tn;

  floatx4 zero4 = {0.f, 0.f, 0.f, 0.f};
  floatx4 acc[8][4];
#pragma unroll
  for (int i = 0; i < 8; i++)
#pragma unroll
    for (int j = 0; j < 4; j++) acc[i][j] = zero4;

  short8 aR[4][2], bR[2][2];

  // prologue: stage K-tile 0 into buf0 (same order as steady state)
  STAGE_A(0, 0, 0);
  STAGE_B(0, 0, 0);
  STAGE_B(0, 1, 0);
  STAGE_A(0, 1, 0);

  const int nkb = 4 * (mt + 1);              // causal K-tiles only (s < 256*(mt+1))
  for (int t = 0; t < nkb; t++) {
    int buf = t & 1, nbuf = buf ^ 1;
    int tn = (t < nkb - 1) ? t + 1 : nkb - 1;  // clamp: last iter restages (harmless)
    KTILE_BODY(buf, nbuf, tn);
  }
  asm volatile("s_waitcnt vmcnt(0)" ::: "memory");  // drain before endpgm

  // tail: per-column suffix sum of v over s >= 256*(mt+1)
  float tl[4];
#pragma unroll
  for (int j = 0; j < 4; j++) {
    int col = bn + (j >> 1) * 128 + wn * 32 + (j & 1) * 16 + (lane & 15);
    tl[j] = Stail[(size_t)h * 8192 + mt * 1024 + col];
  }

  // epilogue: (acc + tail) / denom, scatter col=(b,d) -> outp[b][row][h*64+d]
#pragma unroll
  for (int i = 0; i < 8; i++) {
    int rb = bm + (i >> 2) * 128 + wm * 64 + (i & 3) * 16 + (lane >> 4) * 4;
#pragma unroll
    for (int r = 0; r < 4; r++) {
      int row = rb + r;
      float sc = 1.f / denom[(size_t)h * Tn + row];
#pragma unroll
      for (int j = 0; j < 4; j++) {
        int col = bn + (j >> 1) * 128 + wn * 32 + (j & 1) * 16 + (lane & 15);
        int b = col >> 6, d = col & 63;
        outp[((size_t)(b * Tn + row)) * En + h * HDn + d] = f2bf((acc[i][j][r] + tl[j]) * sc);
      }
    }
  }
}

// ================= GEMM 3: out = o@Wo^T + bo, 256x256 block (round-2 skeleton) =================
__global__ __launch_bounds__(512, 2)
void k_gemm_out(const unsigned short* __restrict__ A, const unsigned short* __restrict__ Bm,
                const float* __restrict__ bias, float* __restrict__ out) {
  __shared__ unsigned short smem[65536];     // 128 KiB
  const int K = 1024, N = 1024;
  int tid = threadIdx.x;
  int wave = tid >> 6, lane = tid & 63;
  int wm = wave >> 2, wn = wave & 3;

  int flat = blockIdx.y * 8 + blockIdx.x;    // gridDim = (8, 64)
  int wg = (flat & 7) * 64 + (flat >> 3);    // 512 blocks: 128 mt x 4 nt
  int mt = wg >> 2, nt = wg & 3;
  int bm = mt * 256, bn = nt * 256;

  const unsigned short* Ap = A;
  const unsigned short* Bp = Bm;

  floatx4 zero4 = {0.f, 0.f, 0.f, 0.f};
  floatx4 acc[8][4];
#pragma unroll
  for (int i = 0; i < 8; i++)
#pragma unroll
    for (int j = 0; j < 4; j++) acc[i][j] = zero4;

  short8 aR[4][2], bR[2][2];

  STAGE_A(0, 0, 0);
  STAGE_B(0, 0, 0);
  STAGE_B(0, 1, 0);
  STAGE_A(0, 1, 0);

  const int nk = K / 64;                     // 16
  for (int t = 0; t < nk; t++) {
    int buf = t & 1, nbuf = buf ^ 1;
    int tn = (t < nk - 1) ? t + 1 : nk - 1;
    KTILE_BODY(buf, nbuf, tn);
  }
  asm volatile("s_waitcnt vmcnt(0)" ::: "memory");

#pragma unroll
  for (int i = 0; i < 8; i++) {
    int rb = bm + (i >> 2) * 128 + wm * 64 + (i & 3) * 16 + (lane >> 4) * 4;
#pragma unroll
    for (int r = 0; r < 4; r++) {
      int row = rb + r;
#pragma unroll
      for (int j = 0; j < 4; j++) {
        int col = bn + (j >> 1) * 128 + wn * 32 + (j & 1) * 16 + (lane & 15);
        out[(size_t)row * N + col] = acc[i][j][r] + bias[col];
      }
    }
  }
}

extern "C" void kernel_launch(void* const* d_in, const int* in_sizes, int n_in,
                              void* d_out, int out_size, void* d_ws, size_t ws_size,
                              hipStream_t stream) {
  const float* x      = (const float*)d_in[0];
  // d_in[1..4] = Wq, bq, Wk, bk — unused by the reference
  const float* Wv     = (const float*)d_in[5];
  const float* bv     = (const float*)d_in[6];
  const float* A_log  = (const float*)d_in[7];
  const float* A_bias = (const float*)d_in[8];
  const float* L      = (const float*)d_in[9];
  const float* Lb     = (const float*)d_in[10];
  const float* Wo     = (const float*)d_in[11];
  const float* bo     = (const float*)d_in[12];
  const int* levels   = (const int*)d_in[13];
  float* out = (float*)d_out;

  // workspace layout (bytes); Pw aliases xb (dead after k_gemm_v)
  char* ws = (char*)d_ws;
  float* csT           = (float*)(ws + 0);                  // 128 KiB (cs, h-major)
  float* denom         = (float*)(ws + 131072);             // 128 KiB
  unsigned short* Wvb  = (unsigned short*)(ws + 262144);    // 2 MiB
  unsigned short* Wob  = (unsigned short*)(ws + 2359296);   // 2 MiB
  unsigned short* xb   = (unsigned short*)(ws + 4456448);   // 64 MiB
  unsigned short* Pw   = (unsigned short*)(ws + 4456448);   // 128 MiB (aliases xb)
  unsigned short* vt   = (unsigned short*)(ws + 138674176); // 64 MiB
  unsigned short* outp = (unsigned short*)(ws + 205783040); // 64 MiB
  if (ws_size < 272891904ULL) return;

  // Stail scratch lives in the tail of d_out (512 KiB); gemm_out overwrites it
  // at the end, and the stream order k_tail -> k_gemm_attn -> k_gemm_out makes
  // the aliasing safe.
  float* Stail = out + (33554432 - 131072);  // out has 33,554,432 floats

  int nx4 = Bn * Tn * En / 4;
  k_cvt<<<(nx4 + 255) / 256, 256, 0, stream>>>(x, xb, nx4);
  int nw4 = En * En / 4;
  k_cvt<<<(nw4 + 255) / 256, 256, 0, stream>>>(Wv, Wvb, nw4);
  k_cvt<<<(nw4 + 255) / 256, 256, 0, stream>>>(Wo, Wob, nw4);
  k_scan<<<NHn, 256, 0, stream>>>(A_log, A_bias, csT);

  k_gemm_v<<<dim3(8, 128), 512, 0, stream>>>(xb, Wvb, bv, vt);

  k_tail<<<NHn * 1024, 256, 0, stream>>>(vt, Stail);

  k_weights<<<Tn, 256, 0, stream>>>(L, Lb, levels, csT, Pw, denom);

  k_gemm_attn<<<dim3(8, 64), 512, 0, stream>>>(Pw, vt, denom, Stail, outp);

  k_gemm_out<<<dim3(8, 64), 512, 0, stream>>>(outp, Wob, bo, out);
}

// Round 12
// 511.043 us; speedup vs baseline: 1.3819x; 1.0636x over previous
//
#include <hip/hip_runtime.h>
#include <stdint.h>

static constexpr int Bn = 16, Tn = 2048, En = 1024, NHn = 16, HDn = 64, NLEVn = 12;

typedef __attribute__((ext_vector_type(8))) short short8;
typedef __attribute__((ext_vector_type(4))) float floatx4;

__device__ __forceinline__ unsigned short f2bf(float f) {
  unsigned int u = __float_as_uint(f);
  u += 0x7fffu + ((u >> 16) & 1u);
  return (unsigned short)(u >> 16);
}
__device__ __forceinline__ float bf2f(unsigned short s) {
  return __uint_as_float(((unsigned int)s) << 16);
}

__device__ __forceinline__ void async16(const unsigned short* g, unsigned short* l) {
  __builtin_amdgcn_global_load_lds(
      (const __attribute__((address_space(1))) unsigned int*)g,
      (__attribute__((address_space(3))) unsigned int*)l, 16, 0, 0);
}

// ---------------- fused pre-pass: scan (blocks 0..15) + all fp32->bf16 cvts ----------------
// Block-uniform branch; scan's 16 blocks hide under the 34816 cvt blocks.
static constexpr int NX4 = Bn * Tn * En / 4;   // 8,388,608
static constexpr int NW4 = En * En / 4;        // 262,144

__global__ void k_pre(const float* __restrict__ x, unsigned short* __restrict__ xb,
                      const float* __restrict__ Wv, unsigned short* __restrict__ Wvb,
                      const float* __restrict__ Wo, unsigned short* __restrict__ Wob,
                      const float* __restrict__ A_log, const float* __restrict__ A_bias,
                      float* __restrict__ csT) {
  int blk = blockIdx.x;
  int tid = threadIdx.x;
  if (blk < 16) {
    // ---- per-head prefix scan of log(sigmoid(A)) -> csT[h][t] ----
    int h = blk;
    __shared__ float part[256];
    float loc[8];
    float run = 0.f;
#pragma unroll
    for (int j = 0; j < 8; j++) {
      int t = tid * 8 + j;
      float xx = A_log[t * NHn + h] + A_bias[t * NHn + h];
      float ls = -log1pf(__expf(-xx));
      run += ls;
      loc[j] = run;
    }
    part[tid] = run;
    __syncthreads();
    for (int d = 1; d < 256; d <<= 1) {
      float v = (tid >= d) ? part[tid - d] : 0.f;
      __syncthreads();
      part[tid] += v;
      __syncthreads();
    }
    float off = (tid > 0) ? part[tid - 1] : 0.f;
#pragma unroll
    for (int j = 0; j < 8; j++) csT[(size_t)h * Tn + tid * 8 + j] = loc[j] + off;
    return;
  }
  // ---- cvt: ranges [0,NX4) -> x, [NX4,NX4+NW4) -> Wv, [NX4+NW4,NX4+2NW4) -> Wo ----
  int i = (blk - 16) * 256 + tid;
  const float* src;
  unsigned short* dst;
  int base;
  if (i < NX4) { src = x; dst = xb; base = 0; }
  else if (i < NX4 + NW4) { src = Wv; dst = Wvb; base = NX4; }
  else if (i < NX4 + 2 * NW4) { src = Wo; dst = Wob; base = NX4 + NW4; }
  else return;
  int k = i - base;
  float4 v = ((const float4*)src)[k];
  ushort4 o;
  o.x = f2bf(v.x); o.y = f2bf(v.y); o.z = f2bf(v.z); o.w = f2bf(v.w);
  ((ushort4*)dst)[k] = o;
}

// ---------------- fused weights (blocks 0..2047) + v-suffix-sums (blocks 2048+) ----------------
// weights: P[h][t][s] for s < Bt = 256*(t/256+1); s>=Bt handled analytically
// (denom += Tn-Bt here; attn adds Stail). tail: Stail[h][mt][col].
__global__ void k_wt(const float* __restrict__ L, const float* __restrict__ Lb,
                     const int* __restrict__ levels, const float* __restrict__ csT,
                     unsigned short* __restrict__ P, float* __restrict__ denom,
                     const unsigned short* __restrict__ vt, float* __restrict__ Stail) {
  int tid = threadIdx.x;
  if (blockIdx.x < Tn) {
    int t = blockIdx.x;
    __shared__ float Lrow[NHn * NLEVn];
    __shared__ float cst[NHn];
    __shared__ float dsum[NHn];
    if (tid < NHn * NLEVn) Lrow[tid] = L[t * NHn * NLEVn + tid] + Lb[t * NHn * NLEVn + tid];
    if (tid < NHn) { cst[tid] = csT[(size_t)tid * Tn + t]; dsum[tid] = 0.f; }
    __syncthreads();
    int Bt = ((t >> 8) + 1) << 8;
    float acc[NHn];
#pragma unroll
    for (int h = 0; h < NHn; h++) acc[h] = 0.f;
    for (int s = tid; s < Bt; s += 256) {
      int lev = levels[(size_t)t * Tn + s];
      bool causal = (s <= t);
#pragma unroll
      for (int h = 0; h < NHn; h++) {
        float w = 1.f;   // exp(0) for s > t
        if (causal) {
          float csr = csT[(size_t)h * Tn + s];      // coalesced: 4 B/lane
          float dec = __expf(cst[h] - csr);
          w = __expf(Lrow[h * NLEVn + lev] * dec);
        }
        unsigned short pb = f2bf(w);
        acc[h] += bf2f(pb);
        P[((size_t)h * Tn + t) * Tn + s] = pb;
      }
    }
    int lane = tid & 63;
#pragma unroll
    for (int h = 0; h < NHn; h++) {
      float v = acc[h];
      for (int o = 32; o > 0; o >>= 1) v += __shfl_down(v, o, 64);
      if (lane == 0) atomicAdd(&dsum[h], v);
    }
    __syncthreads();
    if (tid < NHn) denom[(size_t)tid * Tn + t] = dsum[tid] + (float)(Tn - Bt);
  } else {
    int row = blockIdx.x - Tn;     // h*1024 + col, col=(b<<6)|d
    __shared__ float C[8];
    short8 v = *(const short8*)&vt[(size_t)row * Tn + tid * 8];
    float p = 0.f;
#pragma unroll
    for (int e = 0; e < 8; e++) p += bf2f((unsigned short)v[e]);
#pragma unroll
    for (int o = 16; o > 0; o >>= 1) p += __shfl_xor(p, o, 64);
    if ((tid & 31) == 0) C[tid >> 5] = p;
    __syncthreads();
    if (tid < 8) {
      float s = 0.f;
      for (int k = tid + 1; k < 8; k++) s += C[k];
      int h = row >> 10, col = row & 1023;
      Stail[(size_t)h * 8192 + tid * 1024 + col] = s;
    }
  }
}

// ================= GEMM 1: v = x@Wv^T + bv, 256x128 block, fused transpose =================
// (round-0 proven version: 48 KiB LDS, 2 blocks/CU)
__global__ __launch_bounds__(512)
void k_gemm_v(const unsigned short* __restrict__ A, const unsigned short* __restrict__ Bm,
              const float* __restrict__ bias, unsigned short* __restrict__ vt) {
  __shared__ unsigned short smem[24576];     // 48 KB: As(32K) | Bs(16K); epilogue reuses as Ct
  unsigned short* As = smem;                 // 256 x 64
  unsigned short* Bs = smem + 16384;         // 128 x 64
  const int K = 1024;
  int tid = threadIdx.x;
  int wave = tid >> 6, lane = tid & 63;
  int wm = wave >> 1, wn = wave & 1;         // 4 x 2 waves of 64x64 tiles

  int flat = blockIdx.y * 8 + blockIdx.x;    // gridDim.x == 8
  int xcd = flat & 7, slot = flat >> 3;      // slot 0..127
  int strip = xcd * 16 + (slot >> 3);        // 128 strips, 16 per XCD
  int nt = slot & 7;
  int bm = strip * 256, bn = nt * 128;

  floatx4 zero4 = {0.f, 0.f, 0.f, 0.f};
  floatx4 acc[4][4];
#pragma unroll
  for (int i = 0; i < 4; i++)
#pragma unroll
    for (int j = 0; j < 4; j++) acc[i][j] = zero4;

  for (int k0 = 0; k0 < K; k0 += 64) {
    __syncthreads();
#pragma unroll
    for (int j = 0; j < 4; j++) {            // A: 256 rows x 64 k (32KB)
      int f = j * 512 + tid;
      int r = f >> 3, c = f & 7;
      int cg = c ^ (r & 7);
      async16(&A[(size_t)(bm + r) * K + k0 + cg * 8], &As[f * 8]);
    }
#pragma unroll
    for (int j = 0; j < 2; j++) {            // B: 128 rows x 64 k (16KB)
      int f = j * 512 + tid;
      int r = f >> 3, c = f & 7;
      int cg = c ^ (r & 7);
      async16(&Bm[(size_t)(bn + r) * K + k0 + cg * 8], &Bs[f * 8]);
    }
    __syncthreads();
#pragma unroll
    for (int kk = 0; kk < 2; kk++) {
      short8 af[4], bfr[4];
      int cgk = kk * 4 + (lane >> 4);
#pragma unroll
      for (int i = 0; i < 4; i++) {
        int m = wm * 64 + i * 16 + (lane & 15);
        af[i] = *(const short8*)&As[m * 64 + ((cgk ^ (m & 7)) * 8)];
        int n = wn * 64 + i * 16 + (lane & 15);
        bfr[i] = *(const short8*)&Bs[n * 64 + ((cgk ^ (n & 7)) * 8)];
      }
#pragma unroll
      for (int i = 0; i < 4; i++)
#pragma unroll
        for (int j = 0; j < 4; j++)
          acc[i][j] = __builtin_amdgcn_mfma_f32_16x16x32_bf16(af[i], bfr[j], acc[i][j], 0, 0, 0);
    }
  }

  // ---- fused transpose epilogue: write vt[h][b][d][t] ----
  int b = bm >> 11, t0 = bm & 2047;
  unsigned short* Ct = smem;                 // 64 cols x (256+8) rows
  const int S = 264;
#pragma unroll 1
  for (int pass = 0; pass < 2; pass++) {
    __syncthreads();
    if (wn == pass) {
#pragma unroll
      for (int i = 0; i < 4; i++) {
#pragma unroll
        for (int j = 0; j < 4; j++) {
          int colL = j * 16 + (lane & 15);
          float bia = bias[bn + pass * 64 + colL];
          int rowb = wm * 64 + i * 16 + (lane >> 4) * 4;
          ushort4 p;
          p.x = f2bf(acc[i][j][0] + bia);
          p.y = f2bf(acc[i][j][1] + bia);
          p.z = f2bf(acc[i][j][2] + bia);
          p.w = f2bf(acc[i][j][3] + bia);
          *(ushort4*)&Ct[colL * S + rowb] = p;
        }
      }
    }
    __syncthreads();
#pragma unroll
    for (int cc = 0; cc < 4; cc++) {
      int colL = wave * 8 + cc * 2 + (lane >> 5);
      int gc = bn + pass * 64 + colL;
      int h = gc >> 6, d = gc & 63;
      int tt = (lane & 31) * 8;
      short8 v = *(const short8*)&Ct[colL * S + tt];
      *(short8*)&vt[((size_t)((h * Bn + b) * HDn + d)) * Tn + t0 + tt] = v;
    }
  }
}

// ================= shared 256x256 BK=64 macros (round-2 verified) =================

#define STAGE_A(kt, half, buf)                                                   \
  {                                                                              \
    _Pragma("unroll")                                                            \
    for (int j_ = 0; j_ < 2; j_++) {                                             \
      int f_ = j_ * 512 + tid;                                                   \
      int r_ = f_ >> 3, c_ = f_ & 7;                                             \
      int cg_ = c_ ^ (r_ & 7);                                                   \
      async16(&Ap[(size_t)(bm + (half) * 128 + r_) * K + (kt) * 64 + cg_ * 8],   \
              &smem[(buf) * 32768 + ((half) * 128 + r_) * 64 + c_ * 8]);         \
    }                                                                            \
  }

#define STAGE_B(kt, half, buf)                                                   \
  {                                                                              \
    _Pragma("unroll")                                                            \
    for (int j_ = 0; j_ < 2; j_++) {                                             \
      int f_ = j_ * 512 + tid;                                                   \
      int r_ = f_ >> 3, c_ = f_ & 7;                                             \
      int cg_ = c_ ^ (r_ & 7);                                                   \
      async16(&Bp[(size_t)(bn + (half) * 128 + r_) * K + (kt) * 64 + cg_ * 8],   \
              &smem[(buf) * 32768 + 16384 + ((half) * 128 + r_) * 64 + c_ * 8]); \
    }                                                                            \
  }

#define LOAD_A(buf, Mh)                                                          \
  {                                                                              \
    _Pragma("unroll")                                                            \
    for (int ii_ = 0; ii_ < 4; ii_++) {                                          \
      int m_ = (Mh) * 128 + wm * 64 + ii_ * 16 + (lane & 15);                    \
      _Pragma("unroll")                                                          \
      for (int kk_ = 0; kk_ < 2; kk_++) {                                        \
        int cgk_ = kk_ * 4 + (lane >> 4);                                        \
        aR[ii_][kk_] =                                                           \
            *(const short8*)&smem[(buf) * 32768 + m_ * 64 + ((cgk_ ^ (m_ & 7)) * 8)]; \
      }                                                                          \
    }                                                                            \
  }

#define LOAD_B(buf, Nh)                                                          \
  {                                                                              \
    _Pragma("unroll")                                                            \
    for (int jj_ = 0; jj_ < 2; jj_++) {                                          \
      int n_ = (Nh) * 128 + wn * 32 + jj_ * 16 + (lane & 15);                    \
      _Pragma("unroll")                                                          \
      for (int kk_ = 0; kk_ < 2; kk_++) {                                        \
        int cgk_ = kk_ * 4 + (lane >> 4);                                        \
        bR[jj_][kk_] = *(const short8*)&smem[(buf) * 32768 + 16384 + n_ * 64 +   \
                                             ((cgk_ ^ (n_ & 7)) * 8)];           \
      }                                                                          \
    }                                                                            \
  }

#define MFMA16(Mh, Nh)                                                           \
  {                                                                              \
    __builtin_amdgcn_s_setprio(1);                                               \
    _Pragma("unroll")                                                            \
    for (int kk_ = 0; kk_ < 2; kk_++)                                            \
      _Pragma("unroll")                                                          \
      for (int ii_ = 0; ii_ < 4; ii_++)                                          \
        _Pragma("unroll")                                                        \
        for (int jj_ = 0; jj_ < 2; jj_++)                                        \
          acc[(Mh) * 4 + ii_][(Nh) * 2 + jj_] = __builtin_amdgcn_mfma_f32_16x16x32_bf16( \
              aR[ii_][kk_], bR[jj_][kk_], acc[(Mh) * 4 + ii_][(Nh) * 2 + jj_], 0, 0, 0); \
    __builtin_amdgcn_s_setprio(0);                                               \
  }

#define WAIT6 asm volatile("s_waitcnt vmcnt(6)" ::: "memory")
#define BAR                                                                      \
  {                                                                              \
    asm volatile("" ::: "memory");                                               \
    __builtin_amdgcn_s_barrier();                                                \
    asm volatile("" ::: "memory");                                               \
  }

#define KTILE_BODY(buf, nbuf, tn)                                                \
  {                                                                              \
    /* P1: quadrant (0,0) — needs Ah0[t], Bh0[t] */                              \
    STAGE_A(tn, 0, nbuf);                                                        \
    WAIT6; BAR;                                                                  \
    LOAD_A(buf, 0);                                                              \
    LOAD_B(buf, 0);                                                              \
    MFMA16(0, 0);                                                                \
    BAR;                                                                         \
    /* P2: quadrant (0,1) — needs Bh1[t], reuses aR */                           \
    STAGE_B(tn, 0, nbuf);                                                        \
    WAIT6; BAR;                                                                  \
    LOAD_B(buf, 1);                                                              \
    MFMA16(0, 1);                                                                \
    BAR;                                                                         \
    /* P3: quadrant (1,1) — needs Ah1[t], reuses bR */                           \
    STAGE_B(tn, 1, nbuf);                                                        \
    WAIT6; BAR;                                                                  \
    LOAD_A(buf, 1);                                                              \
    MFMA16(1, 1);                                                                \
    BAR;                                                                         \
    /* P4: quadrant (1,0) — re-reads Bh0[t], reuses aR */                        \
    STAGE_A(tn, 1, nbuf);                                                        \
    WAIT6; BAR;                                                                  \
    LOAD_B(buf, 0);                                                              \
    MFMA16(1, 0);                                                                \
    BAR;                                                                         \
  }

// ================= GEMM 2: attn @ v (per head), causal-range K-loop =================
// Work per block = 4*(mt+1) K-tiles; complementary-mt pairing balances CUs.
__global__ __launch_bounds__(512, 2)
void k_gemm_attn(const unsigned short* __restrict__ P, const unsigned short* __restrict__ vt,
                 const float* __restrict__ denom, const float* __restrict__ Stail,
                 unsigned short* __restrict__ outp) {
  __shared__ unsigned short smem[65536];     // 128 KiB: 2 x (A 256x64 | B 256x64)
  const int K = Tn;
  int tid = threadIdx.x;
  int wave = tid >> 6, lane = tid & 63;
  int wm = wave >> 2, wn = wave & 3;         // per-quadrant: 2x4 waves of 64x32

  int flat = blockIdx.y * 8 + blockIdx.x;    // gridDim = (8, 64)
  int xcd = flat & 7, slot = flat >> 3;      // slot 0..63 within XCD
  int h = xcd * 2 + (slot >> 5);             // 2 heads per XCD
  int mtraw = (slot >> 2) & 7;
  int mt = (slot & 32) ? (7 - mtraw) : mtraw;  // complementary-mt pairing
  int nt = slot & 3;
  int bm = mt * 256, bn = nt * 256;

  const unsigned short* Ap = P + (size_t)h * Tn * Tn;
  const unsigned short* Bp = vt + (size_t)h * (Bn * HDn) * Tn;

  floatx4 zero4 = {0.f, 0.f, 0.f, 0.f};
  floatx4 acc[8][4];
#pragma unroll
  for (int i = 0; i < 8; i++)
#pragma unroll
    for (int j = 0; j < 4; j++) acc[i][j] = zero4;

  short8 aR[4][2], bR[2][2];

  // prologue: stage K-tile 0 into buf0 (same order as steady state)
  STAGE_A(0, 0, 0);
  STAGE_B(0, 0, 0);
  STAGE_B(0, 1, 0);
  STAGE_A(0, 1, 0);

  const int nkb = 4 * (mt + 1);              // causal K-tiles only (s < 256*(mt+1))
  for (int t = 0; t < nkb; t++) {
    int buf = t & 1, nbuf = buf ^ 1;
    int tn = (t < nkb - 1) ? t + 1 : nkb - 1;  // clamp: last iter restages (harmless)
    KTILE_BODY(buf, nbuf, tn);
  }
  asm volatile("s_waitcnt vmcnt(0)" ::: "memory");  // drain before endpgm

  // tail: per-column suffix sum of v over s >= 256*(mt+1)
  float tl[4];
#pragma unroll
  for (int j = 0; j < 4; j++) {
    int col = bn + (j >> 1) * 128 + wn * 32 + (j & 1) * 16 + (lane & 15);
    tl[j] = Stail[(size_t)h * 8192 + mt * 1024 + col];
  }

  // epilogue: (acc + tail) / denom, scatter col=(b,d) -> outp[b][row][h*64+d]
#pragma unroll
  for (int i = 0; i < 8; i++) {
    int rb = bm + (i >> 2) * 128 + wm * 64 + (i & 3) * 16 + (lane >> 4) * 4;
#pragma unroll
    for (int r = 0; r < 4; r++) {
      int row = rb + r;
      float sc = 1.f / denom[(size_t)h * Tn + row];
#pragma unroll
      for (int j = 0; j < 4; j++) {
        int col = bn + (j >> 1) * 128 + wn * 32 + (j & 1) * 16 + (lane & 15);
        int b = col >> 6, d = col & 63;
        outp[((size_t)(b * Tn + row)) * En + h * HDn + d] = f2bf((acc[i][j][r] + tl[j]) * sc);
      }
    }
  }
}

// ================= GEMM 3: out = o@Wo^T + bo, 256x256 block (round-2 skeleton) =================
__global__ __launch_bounds__(512, 2)
void k_gemm_out(const unsigned short* __restrict__ A, const unsigned short* __restrict__ Bm,
                const float* __restrict__ bias, float* __restrict__ out) {
  __shared__ unsigned short smem[65536];     // 128 KiB
  const int K = 1024, N = 1024;
  int tid = threadIdx.x;
  int wave = tid >> 6, lane = tid & 63;
  int wm = wave >> 2, wn = wave & 3;

  int flat = blockIdx.y * 8 + blockIdx.x;    // gridDim = (8, 64)
  int wg = (flat & 7) * 64 + (flat >> 3);    // 512 blocks: 128 mt x 4 nt
  int mt = wg >> 2, nt = wg & 3;
  int bm = mt * 256, bn = nt * 256;

  const unsigned short* Ap = A;
  const unsigned short* Bp = Bm;

  floatx4 zero4 = {0.f, 0.f, 0.f, 0.f};
  floatx4 acc[8][4];
#pragma unroll
  for (int i = 0; i < 8; i++)
#pragma unroll
    for (int j = 0; j < 4; j++) acc[i][j] = zero4;

  short8 aR[4][2], bR[2][2];

  STAGE_A(0, 0, 0);
  STAGE_B(0, 0, 0);
  STAGE_B(0, 1, 0);
  STAGE_A(0, 1, 0);

  const int nk = K / 64;                     // 16
  for (int t = 0; t < nk; t++) {
    int buf = t & 1, nbuf = buf ^ 1;
    int tn = (t < nk - 1) ? t + 1 : nk - 1;
    KTILE_BODY(buf, nbuf, tn);
  }
  asm volatile("s_waitcnt vmcnt(0)" ::: "memory");

#pragma unroll
  for (int i = 0; i < 8; i++) {
    int rb = bm + (i >> 2) * 128 + wm * 64 + (i & 3) * 16 + (lane >> 4) * 4;
#pragma unroll
    for (int r = 0; r < 4; r++) {
      int row = rb + r;
#pragma unroll
      for (int j = 0; j < 4; j++) {
        int col = bn + (j >> 1) * 128 + wn * 32 + (j & 1) * 16 + (lane & 15);
        out[(size_t)row * N + col] = acc[i][j][r] + bias[col];
      }
    }
  }
}

extern "C" void kernel_launch(void* const* d_in, const int* in_sizes, int n_in,
                              void* d_out, int out_size, void* d_ws, size_t ws_size,
                              hipStream_t stream) {
  const float* x      = (const float*)d_in[0];
  // d_in[1..4] = Wq, bq, Wk, bk — unused by the reference
  const float* Wv     = (const float*)d_in[5];
  const float* bv     = (const float*)d_in[6];
  const float* A_log  = (const float*)d_in[7];
  const float* A_bias = (const float*)d_in[8];
  const float* L      = (const float*)d_in[9];
  const float* Lb     = (const float*)d_in[10];
  const float* Wo     = (const float*)d_in[11];
  const float* bo     = (const float*)d_in[12];
  const int* levels   = (const int*)d_in[13];
  float* out = (float*)d_out;

  // workspace layout (bytes); Pw aliases xb (dead after k_gemm_v)
  char* ws = (char*)d_ws;
  float* csT           = (float*)(ws + 0);                  // 128 KiB (cs, h-major)
  float* denom         = (float*)(ws + 131072);             // 128 KiB
  unsigned short* Wvb  = (unsigned short*)(ws + 262144);    // 2 MiB
  unsigned short* Wob  = (unsigned short*)(ws + 2359296);   // 2 MiB
  unsigned short* xb   = (unsigned short*)(ws + 4456448);   // 64 MiB
  unsigned short* Pw   = (unsigned short*)(ws + 4456448);   // 128 MiB (aliases xb)
  unsigned short* vt   = (unsigned short*)(ws + 138674176); // 64 MiB
  unsigned short* outp = (unsigned short*)(ws + 205783040); // 64 MiB
  if (ws_size < 272891904ULL) return;

  // Stail scratch lives in the tail of d_out (512 KiB); gemm_out overwrites it
  // at the end; stream order k_wt -> k_gemm_attn -> k_gemm_out keeps it safe.
  float* Stail = out + (33554432 - 131072);  // out has 33,554,432 floats

  // 1) fused scan + cvts (16 scan blocks + 34816 cvt blocks)
  int npre = 16 + (NX4 + 2 * NW4) / 256;
  k_pre<<<npre, 256, 0, stream>>>(x, xb, Wv, Wvb, Wo, Wob, A_log, A_bias, csT);

  // 2) v-projection GEMM
  k_gemm_v<<<dim3(8, 128), 512, 0, stream>>>(xb, Wvb, bv, vt);

  // 3) fused weights + v-suffix-sums (2048 weights blocks + 16384 tail blocks)
  k_wt<<<Tn + NHn * 1024, 256, 0, stream>>>(L, Lb, levels, csT, Pw, denom, vt, Stail);

  // 4) attn GEMM (causal range + analytic tail)
  k_gemm_attn<<<dim3(8, 64), 512, 0, stream>>>(Pw, vt, denom, Stail, outp);

  // 5) output GEMM
  k_gemm_out<<<dim3(8, 64), 512, 0, stream>>>(outp, Wob, bo, out);
}